// Round 9
// baseline (459.485 us; speedup 1.0000x reference)
//
#include <hip/hip_runtime.h>
#include <math.h>

#define N 16384
#define KNN 16

typedef __attribute__((ext_vector_type(8))) short bf16x8;
typedef __attribute__((ext_vector_type(4))) float f32x4;
typedef unsigned short ushort_t;
typedef unsigned long long u64;

__device__ __forceinline__ float lrelu(float a) { return a > 0.f ? a : 0.01f * a; }

__device__ __forceinline__ ushort_t f2bf(float f) {
  unsigned u = __float_as_uint(f);
  u += 0x7FFF + ((u >> 16) & 1);
  return (ushort_t)(u >> 16);
}
__device__ __forceinline__ float bf2f(ushort_t h) {
  return __uint_as_float((unsigned)h << 16);
}
__device__ __forceinline__ int lanerank(u64 mask) {
  return __builtin_amdgcn_mbcnt_hi((unsigned)(mask >> 32),
         __builtin_amdgcn_mbcnt_lo((unsigned)mask, 0));
}

// ---------------------------------------------------------------------------
// prepw: fused prep (blocks 0..255) + weight conversion (blocks 256..551).
// ---------------------------------------------------------------------------
#define PPB 64
__global__ __launch_bounds__(256) void prepw_kernel(
    const float* __restrict__ img, const float* __restrict__ cloud,
    const float* __restrict__ p1w, const float* __restrict__ p1b,
    const float* __restrict__ p2w, const float* __restrict__ p2b,
    const float* __restrict__ ps1w, const float* __restrict__ ps2w,
    const float* __restrict__ c1w, const float* __restrict__ c2w,
    float4* __restrict__ pts4, ushort_t* __restrict__ cfh,
    ushort_t* __restrict__ imfh,
    ushort_t* __restrict__ w1h, ushort_t* __restrict__ w2h,
    ushort_t* __restrict__ c1h, ushort_t* __restrict__ c2h) {
  int t = threadIdx.x;
  if (blockIdx.x >= 256) {
    int e = (blockIdx.x - 256) * 256 + t;
    if (e < 32768) w1h[e] = f2bf(ps1w[e]);
    else if (e < 65536) w2h[e - 32768] = f2bf(ps2w[e - 32768]);
    else if (e < 67584) c1h[e - 65536] = f2bf(c1w[e - 65536]);
    else if (e < 75776) c2h[e - 67584] = f2bf(c2w[e - 67584]);
    return;
  }
  __shared__ alignas(16) float w2t[64 * 132];
  __shared__ alignas(16) float hs[PPB * 68];
  __shared__ alignas(16) float w1s[192];
  __shared__ alignas(16) float b1s[64];
  __shared__ alignas(16) float b2s[128];
  __shared__ float ptmp[PPB * 3];
  __shared__ float psx[PPB], psy[PPB], psz[PPB];
  int pb = blockIdx.x * PPB;

  for (int e = t; e < 128 * 64; e += 256) {
    int ch = e >> 6, k = e & 63;
    w2t[k * 132 + ch] = p2w[e];
  }
  if (t < 192) w1s[t] = p1w[t];
  if (t < 64) b1s[t] = p1b[t];
  if (t < 128) b2s[t] = p2b[t];
  if (t < PPB * 3) ptmp[t] = cloud[pb * 3 + t];
  __syncthreads();
  if (t < PPB) {
    float x = ptmp[t * 3], y = ptmp[t * 3 + 1], z = ptmp[t * 3 + 2];
    psx[t] = x; psy[t] = y; psz[t] = z;
    pts4[pb + t] = make_float4(x, y, z, x * x + y * y + z * z);
  }
  for (int e = t; e < 32 * PPB; e += 256) {
    int c = e >> 6, p = e & 63;
    imfh[(size_t)(pb + p) * 32 + c] = f2bf(img[(size_t)c * N + pb + p]);
  }
  __syncthreads();
  for (int e = t; e < PPB * 64; e += 256) {
    int pt_ = e >> 6, ch = e & 63;
    float a = b1s[ch] + psx[pt_] * w1s[ch * 3] + psy[pt_] * w1s[ch * 3 + 1] +
              psz[pt_] * w1s[ch * 3 + 2];
    hs[pt_ * 68 + ch] = lrelu(a);
  }
  __syncthreads();
  for (int e = t; e < PPB * 32; e += 256) {
    int pt_ = e >> 5, c4 = (e & 31) << 2;
    float4 acc = *(const float4*)&b2s[c4];
    const float* hrow = &hs[pt_ * 68];
    #pragma unroll
    for (int k = 0; k < 64; k += 4) {
      float4 h4 = *(const float4*)&hrow[k];
      float4 w0 = *(const float4*)&w2t[(k + 0) * 132 + c4];
      float4 w1_ = *(const float4*)&w2t[(k + 1) * 132 + c4];
      float4 w2_ = *(const float4*)&w2t[(k + 2) * 132 + c4];
      float4 w3 = *(const float4*)&w2t[(k + 3) * 132 + c4];
      acc.x = fmaf(h4.x, w0.x, fmaf(h4.y, w1_.x, fmaf(h4.z, w2_.x, fmaf(h4.w, w3.x, acc.x))));
      acc.y = fmaf(h4.x, w0.y, fmaf(h4.y, w1_.y, fmaf(h4.z, w2_.y, fmaf(h4.w, w3.y, acc.y))));
      acc.z = fmaf(h4.x, w0.z, fmaf(h4.y, w1_.z, fmaf(h4.z, w2_.z, fmaf(h4.w, w3.z, acc.z))));
      acc.w = fmaf(h4.x, w0.w, fmaf(h4.y, w1_.w, fmaf(h4.z, w2_.w, fmaf(h4.w, w3.w, acc.w))));
    }
    unsigned lo = (unsigned)f2bf(acc.x) | ((unsigned)f2bf(acc.y) << 16);
    unsigned hi = (unsigned)f2bf(acc.z) | ((unsigned)f2bf(acc.w) << 16);
    *(uint2*)&cfh[(size_t)(pb + pt_) * 128 + c4] = make_uint2(lo, hi);
  }
}

// ---------------------------------------------------------------------------
// KNN v9 = v6 shape (proven 197 us): 4 query-waves/block, TILE=1024, 20 KB
// LDS -> 8 blocks/CU; d2' filter (qw folded into tau); exact top-16.
// ---------------------------------------------------------------------------
__device__ __forceinline__ u64 bsort64(u64 v, int lane) {
  #pragma unroll
  for (int k = 2; k <= 64; k <<= 1) {
    #pragma unroll
    for (int j = k >> 1; j >= 1; j >>= 1) {
      u64 p = __shfl_xor(v, j);
      bool keepmin = (((lane & j) == 0) == ((lane & k) == 0));
      u64 mn = v < p ? v : p;
      u64 mx = v < p ? p : v;
      v = keepmin ? mn : mx;
    }
  }
  return v;
}

__device__ __forceinline__ u64 bclean64(u64 v, int lane) {
  #pragma unroll
  for (int j = 32; j >= 1; j >>= 1) {
    u64 p = __shfl_xor(v, j);
    u64 mn = v < p ? v : p;
    u64 mx = v < p ? p : v;
    v = ((lane & j) == 0) ? mn : mx;
  }
  return v;
}

__device__ __forceinline__ u64 compact_topk(u64* buf, int& cnt, int lane, float& tau) {
  u64 v = (lane < cnt) ? buf[lane] : ~0ULL;
  v = bsort64(v, lane);
  if (cnt > 64) {
    u64 t = (64 + lane < cnt) ? buf[64 + lane] : ~0ULL;
    t = bsort64(t, lane);
    t = __shfl_xor(t, 63);
    v = (t < v) ? t : v;
    v = bclean64(v, lane);
  }
  if (lane < 16) buf[lane] = v;
  cnt = 16;
  u64 k15 = __shfl(v, 15);
  tau = __uint_as_float((unsigned)(k15 >> 32));
  return v;
}

// conservative tau' = tau - qw (padded: filter never rejects a true top-16 key)
__device__ __forceinline__ float tadj(float tau, float qw) {
  float a = tau - qw;
  return a + fabsf(a) * 2e-7f + 1e-35f;
}

#define TILE 1024
__global__ __launch_bounds__(256) void knn_kernel(
    const float4* __restrict__ pts4, int* __restrict__ nidx, float* __restrict__ nwgt) {
  __shared__ alignas(16) float4 tile[TILE];  // 16 KB
  __shared__ u64 sbuf[4][128];               // 4 KB
  int t = threadIdx.x;
  int wv = t >> 6, lane = t & 63;
  int wid = blockIdx.x * 4 + wv;
  u64* buf = sbuf[wv];

  float4 q = pts4[wid];
  float q2x = -2.f * q.x, q2y = -2.f * q.y, q2z = -2.f * q.z, qw = q.w;
  float tau, ta;
  int cnt;

  // seed: candidates 0..63 -> sorted -> tight initial tau
  {
    float4 c = pts4[lane];
    float d2 = fmaf(q2x, c.x, fmaf(q2y, c.y, fmaf(q2z, c.z, qw + c.w)));
    u64 v = ((u64)__float_as_uint(fmaxf(d2, 0.f)) << 32) | (unsigned)lane;
    v = bsort64(v, lane);
    if (lane < 16) buf[lane] = v;
    u64 k15 = __shfl(v, 15);
    tau = __uint_as_float((unsigned)(k15 >> 32));
    ta = tadj(tau, qw);
    cnt = 16;
  }

  for (int base = 0; base < N; base += TILE) {
    __syncthreads();
    for (int e = t; e < TILE; e += 256) tile[e] = pts4[base + e];
    __syncthreads();
    for (int s = (base == 0 ? 64 : 0); s < TILE; s += 64) {
      float4 c = tile[s + lane];
      float d2 = fmaf(q2x, c.x, fmaf(q2y, c.y, fmaf(q2z, c.z, c.w)));
      bool pass = (d2 <= ta);
      u64 mask = __ballot(pass);
      if (mask) {
        if (pass) {
          u64 key = ((u64)__float_as_uint(fmaxf(d2 + qw, 0.f)) << 32) |
                    (unsigned)(base + s + lane);
          buf[cnt + lanerank(mask)] = key;
        }
        cnt += __popcll(mask);
        if (cnt > 64) {
          compact_topk(buf, cnt, lane, tau);
          ta = tadj(tau, qw);
        }
      }
    }
  }
  u64 v = compact_topk(buf, cnt, lane, tau);

  int id = (lane < KNN) ? (int)(unsigned)(v & 0xffffffffULL) : 0;
  float4 c = pts4[id];
  float dx = q.x - c.x, dy = q.y - c.y, dz = q.z - c.z;
  float dist = sqrtf(fmaxf(dx * dx + dy * dy + dz * dz, 1e-12f));
  float md = (lane < KNN) ? dist : INFINITY;
  #pragma unroll
  for (int off = 1; off < KNN; off <<= 1) md = fminf(md, __shfl_xor(md, off));
  float e = expf(md - dist);
  float se = (lane < KNN) ? e : 0.f;
  #pragma unroll
  for (int off = 1; off < KNN; off <<= 1) se += __shfl_xor(se, off);
  if (lane < KNN) {
    nidx[wid * KNN + lane] = id;
    nwgt[wid * KNN + lane] = e / se;
  }
}

// ---------------------------------------------------------------------------
// mega v2: sf + sfp + final fused per 4 points; s1 halved (two 128-ch passes
// of sfp layer1, layer2 accumulates each K-half) -> LDS ~35 KB -> 4 blk/CU.
//   nb[64x136] bf16 (sfp gather)  -> reused as feat[4][448] fp32 at the end
//   s1[64x136] bf16 (half layer1) -> first used as nbi[64x48] + h1[64x72]
// feat imf/cf values prefetched into registers at kernel start.
// ---------------------------------------------------------------------------
#define NB_LD 136
#define SH_LD 136
#define NI_LD 48
#define H1_LD 72
__global__ __launch_bounds__(256) void mega_kernel(
    const ushort_t* __restrict__ cfh, const ushort_t* __restrict__ imfh,
    const int* __restrict__ nidx, const float* __restrict__ nwgt,
    const ushort_t* __restrict__ w1h, const float* __restrict__ b1,
    const ushort_t* __restrict__ w2h, const float* __restrict__ b2,
    const ushort_t* __restrict__ c1h, const float* __restrict__ c1b,
    const ushort_t* __restrict__ c2h, const float* __restrict__ c2b,
    const float* __restrict__ fw, const float* __restrict__ fb,
    float* __restrict__ out) {
  __shared__ ushort_t nb[64 * NB_LD];   // 17408 B
  __shared__ ushort_t s1[64 * SH_LD];   // 17408 B
  __shared__ int ids[64];
  __shared__ float wg[64];
  ushort_t* nbi = s1;                   // 6144 B
  ushort_t* h1 = s1 + 64 * NI_LD;       // 9216 B
  float* feat = (float*)nb;             // 4 x 448 fp32 = 7168 B

  int t = threadIdx.x;
  int w = t >> 6, lane = t & 63;
  int col = lane & 15, quad = lane >> 4;
  int pbase = blockIdx.x * 4;

  // prefetch feat imf/cf inputs (consumed only at the feat-fill phase)
  ushort_t myimf = (t < 128) ? imfh[(size_t)pbase * 32 + t] : 0;
  ushort_t mycf0 = cfh[(size_t)pbase * 128 + t];
  ushort_t mycf1 = cfh[(size_t)pbase * 128 + 256 + t];

  if (t < 64) {
    ids[t] = nidx[pbase * 16 + t];
    wg[t] = nwgt[pbase * 16 + t];
  }
  __syncthreads();
  // gather neighbor rows: nb (cfh, 64x128) and nbi (imfh, 64x32)
  for (int e = t; e < 1024; e += 256) {
    int row = e >> 4, c8 = (e & 15) << 3;
    *(uint4*)&nb[row * NB_LD + c8] = *(const uint4*)&cfh[(size_t)ids[row] * 128 + c8];
  }
  {
    int row = t >> 2, c8 = (t & 3) << 3;
    *(uint4*)&nbi[row * NI_LD + c8] = *(const uint4*)&imfh[(size_t)ids[row] * 32 + c8];
  }
  __syncthreads();

  // ---------------- SF layer1: 32 -> 64 ----------------------------------
  float sfv[2][4];
  {
    f32x4 accA[4];
    #pragma unroll
    for (int p = 0; p < 4; ++p) accA[p] = (f32x4){0.f, 0.f, 0.f, 0.f};
    int n = w * 16 + col;
    bf16x8 b = *(const bf16x8*)&c1h[n * 32 + quad * 8];
    #pragma unroll
    for (int p = 0; p < 4; ++p) {
      bf16x8 a = *(const bf16x8*)&nbi[(p * 16 + col) * NI_LD + quad * 8];
      accA[p] = __builtin_amdgcn_mfma_f32_16x16x32_bf16(a, b, accA[p], 0, 0, 0);
    }
    __syncthreads();  // nbi reads done before h1 writes share the region? (disjoint) — kept for write-order safety
    float bb = c1b[n];
    #pragma unroll
    for (int p = 0; p < 4; ++p)
      #pragma unroll
      for (int r = 0; r < 4; ++r)
        h1[(p * 16 + quad * 4 + r) * H1_LD + n] = f2bf(lrelu(accA[p][r] + bb));
  }
  __syncthreads();
  // ---------------- SF layer2: 64 -> 128 ----------------------------------
  {
    f32x4 acc2[2][4];
    #pragma unroll
    for (int tt = 0; tt < 2; ++tt)
      #pragma unroll
      for (int p = 0; p < 4; ++p) acc2[tt][p] = (f32x4){0.f, 0.f, 0.f, 0.f};
    for (int k0 = 0; k0 < 64; k0 += 32) {
      bf16x8 a[4];
      #pragma unroll
      for (int p = 0; p < 4; ++p)
        a[p] = *(const bf16x8*)&h1[(p * 16 + col) * H1_LD + k0 + quad * 8];
      #pragma unroll
      for (int tt = 0; tt < 2; ++tt) {
        int n = w * 32 + tt * 16 + col;
        bf16x8 b = *(const bf16x8*)&c2h[n * 64 + k0 + quad * 8];
        #pragma unroll
        for (int p = 0; p < 4; ++p)
          acc2[tt][p] = __builtin_amdgcn_mfma_f32_16x16x32_bf16(a[p], b, acc2[tt][p], 0, 0, 0);
      }
    }
    #pragma unroll
    for (int tt = 0; tt < 2; ++tt) {
      int n = w * 32 + tt * 16 + col;
      float bb = c2b[n];
      #pragma unroll
      for (int p = 0; p < 4; ++p) {
        float mx = -INFINITY;
        #pragma unroll
        for (int r = 0; r < 4; ++r)
          mx = fmaxf(mx, (acc2[tt][p][r] + bb) * wg[p * 16 + quad * 4 + r]);
        mx = fmaxf(mx, __shfl_xor(mx, 16));
        mx = fmaxf(mx, __shfl_xor(mx, 32));
        sfv[tt][p] = mx;  // valid on lanes < 16
      }
    }
  }
  __syncthreads();  // h1 dead; s1 region free for sfp layer1

  // ---------------- SFP: layer1 in 2 half-passes, layer2 accumulates ------
  f32x4 acc2[2][4];
  #pragma unroll
  for (int tt = 0; tt < 2; ++tt)
    #pragma unroll
    for (int p = 0; p < 4; ++p) acc2[tt][p] = (f32x4){0.f, 0.f, 0.f, 0.f};

  for (int hb = 0; hb < 2; ++hb) {
    // layer1: channels [hb*128, hb*128+128) -> s1[row][0..128)
    {
      f32x4 acc1[2][4];
      #pragma unroll
      for (int tt = 0; tt < 2; ++tt)
        #pragma unroll
        for (int p = 0; p < 4; ++p) acc1[tt][p] = (f32x4){0.f, 0.f, 0.f, 0.f};
      for (int k0 = 0; k0 < 128; k0 += 32) {
        bf16x8 a[4];
        #pragma unroll
        for (int p = 0; p < 4; ++p)
          a[p] = *(const bf16x8*)&nb[(p * 16 + col) * NB_LD + k0 + quad * 8];
        #pragma unroll
        for (int tt = 0; tt < 2; ++tt) {
          int nl = w * 32 + tt * 16 + col;
          bf16x8 b = *(const bf16x8*)&w1h[(hb * 128 + nl) * 128 + k0 + quad * 8];
          #pragma unroll
          for (int p = 0; p < 4; ++p)
            acc1[tt][p] = __builtin_amdgcn_mfma_f32_16x16x32_bf16(a[p], b, acc1[tt][p], 0, 0, 0);
        }
      }
      #pragma unroll
      for (int tt = 0; tt < 2; ++tt) {
        int nl = w * 32 + tt * 16 + col;
        float bb = b1[hb * 128 + nl];
        #pragma unroll
        for (int p = 0; p < 4; ++p)
          #pragma unroll
          for (int r = 0; r < 4; ++r)
            s1[(p * 16 + quad * 4 + r) * SH_LD + nl] = f2bf(lrelu(acc1[tt][p][r] + bb));
      }
    }
    __syncthreads();
    // layer2: accumulate K in [hb*128, hb*128+128)
    for (int kl = 0; kl < 128; kl += 32) {
      bf16x8 a[4];
      #pragma unroll
      for (int p = 0; p < 4; ++p)
        a[p] = *(const bf16x8*)&s1[(p * 16 + col) * SH_LD + kl + quad * 8];
      #pragma unroll
      for (int tt = 0; tt < 2; ++tt) {
        int n = w * 32 + tt * 16 + col;
        bf16x8 b = *(const bf16x8*)&w2h[n * 256 + hb * 128 + kl + quad * 8];
        #pragma unroll
        for (int p = 0; p < 4; ++p)
          acc2[tt][p] = __builtin_amdgcn_mfma_f32_16x16x32_bf16(a[p], b, acc2[tt][p], 0, 0, 0);
      }
    }
    __syncthreads();  // l2 reads done: allows hb=1 overwrite / feat phase
  }

  // spv: weighted max + bias
  float spv[2][4];
  #pragma unroll
  for (int tt = 0; tt < 2; ++tt) {
    int n = w * 32 + tt * 16 + col;
    float bb = b2[n];
    #pragma unroll
    for (int p = 0; p < 4; ++p) {
      float mx = -INFINITY;
      #pragma unroll
      for (int r = 0; r < 4; ++r)
        mx = fmaxf(mx, (acc2[tt][p][r] + bb) * wg[p * 16 + quad * 4 + r]);
      mx = fmaxf(mx, __shfl_xor(mx, 16));
      mx = fmaxf(mx, __shfl_xor(mx, 32));
      spv[tt][p] = mx;  // valid on lanes < 16
    }
  }

  // ---------------- feat fill (into nb region, lrelu applied) -------------
  // per point: [0,128) sfp | [128,160) imf | [160,288) sf | [288,416) cf | pad
  #pragma unroll
  for (int tt = 0; tt < 2; ++tt)
    #pragma unroll
    for (int p = 0; p < 4; ++p)
      if (lane < 16) {
        feat[p * 448 + w * 32 + tt * 16 + lane] = lrelu(spv[tt][p]);
        feat[p * 448 + 160 + w * 32 + tt * 16 + lane] = lrelu(sfv[tt][p]);
      }
  if (t < 128) {
    feat[(t >> 5) * 448 + 128 + (t & 31)] = lrelu(bf2f(myimf));
    feat[(t >> 5) * 448 + 416 + (t & 31)] = 0.f;  // pad tail
  }
  feat[(t >> 7) * 448 + 288 + (t & 127)] = lrelu(bf2f(mycf0));
  feat[((t + 256) >> 7) * 448 + 288 + ((t + 256) & 127)] = lrelu(bf2f(mycf1));
  __syncthreads();

  // ---------------- final GEMV: 4 points share fw reads --------------------
  // lane: p = lane>>4, sub = lane&15, ch = w*8 + (sub&7), half = sub>>3
  {
    int p = lane >> 4, sub = lane & 15;
    int ch = w * 8 + (sub & 7), half = sub >> 3;
    float acc = half ? 0.f : fb[ch];
    const float* wr = fw + ch * 416 + half * 208;
    const float* fr = feat + p * 448 + half * 208;
    #pragma unroll 4
    for (int j = 0; j < 208; j += 4) {
      float4 w4 = *(const float4*)(wr + j);
      float4 f4 = *(const float4*)(fr + j);
      acc = fmaf(f4.x, w4.x, fmaf(f4.y, w4.y, fmaf(f4.z, w4.z, fmaf(f4.w, w4.w, acc))));
    }
    acc += __shfl_xor(acc, 8);  // combine halves
    if ((sub & 8) == 0) out[(size_t)ch * N + pbase + p] = acc;
  }
}

// ---------------------------------------------------------------------------
extern "C" void kernel_launch(void* const* d_in, const int* in_sizes, int n_in,
                              void* d_out, int out_size, void* d_ws, size_t ws_size,
                              hipStream_t stream) {
  const float* img   = (const float*)d_in[0];
  const float* cloud = (const float*)d_in[1];
  const float* c1w   = (const float*)d_in[2];
  const float* c1b   = (const float*)d_in[3];
  const float* c2w   = (const float*)d_in[4];
  const float* c2b   = (const float*)d_in[5];
  const float* ps1w  = (const float*)d_in[6];
  const float* ps1b  = (const float*)d_in[7];
  const float* ps2w  = (const float*)d_in[8];
  const float* ps2b  = (const float*)d_in[9];
  const float* p1w   = (const float*)d_in[10];
  const float* p1b   = (const float*)d_in[11];
  const float* p2w   = (const float*)d_in[12];
  const float* p2b   = (const float*)d_in[13];
  const float* fw    = (const float*)d_in[14];
  const float* fb    = (const float*)d_in[15];
  float* out = (float*)d_out;

  char* ws = (char*)d_ws;
  float4*   pts4 = (float4*)(ws + 0);              // 256 KB
  ushort_t* cfh  = (ushort_t*)(ws + 262144);       // 4 MB
  ushort_t* imfh = (ushort_t*)(ws + 4456448);      // 1 MB
  int*      nidx = (int*)(ws + 5505024);           // 1 MB
  float*    nwgt = (float*)(ws + 6553600);         // 1 MB
  ushort_t* w1h  = (ushort_t*)(ws + 7602176);      // 64 KB
  ushort_t* w2h  = (ushort_t*)(ws + 7667712);      // 64 KB
  ushort_t* c1h  = (ushort_t*)(ws + 7733248);      // 4 KB
  ushort_t* c2h  = (ushort_t*)(ws + 7737344);      // 16 KB

  prepw_kernel<<<552, 256, 0, stream>>>(img, cloud, p1w, p1b, p2w, p2b,
                                        ps1w, ps2w, c1w, c2w,
                                        pts4, cfh, imfh, w1h, w2h, c1h, c2h);
  knn_kernel<<<N / 4, 256, 0, stream>>>(pts4, nidx, nwgt);
  mega_kernel<<<N / 4, 256, 0, stream>>>(cfh, imfh, nidx, nwgt,
                                         w1h, ps1b, w2h, ps2b,
                                         c1h, c1b, c2h, c2b, fw, fb, out);
}

// Round 10
// 389.088 us; speedup vs baseline: 1.1809x; 1.1809x over previous
//
#include <hip/hip_runtime.h>
#include <math.h>

#define N 16384
#define KNN 16

typedef __attribute__((ext_vector_type(8))) short bf16x8;
typedef __attribute__((ext_vector_type(4))) float f32x4;
typedef unsigned short ushort_t;
typedef unsigned long long u64;

__device__ __forceinline__ float lrelu(float a) { return a > 0.f ? a : 0.01f * a; }

__device__ __forceinline__ ushort_t f2bf(float f) {
  unsigned u = __float_as_uint(f);
  u += 0x7FFF + ((u >> 16) & 1);
  return (ushort_t)(u >> 16);
}
__device__ __forceinline__ float bf2f(ushort_t h) {
  return __uint_as_float((unsigned)h << 16);
}
__device__ __forceinline__ int lanerank(u64 mask) {
  return __builtin_amdgcn_mbcnt_hi((unsigned)(mask >> 32),
         __builtin_amdgcn_mbcnt_lo((unsigned)mask, 0));
}

// ---------------------------------------------------------------------------
// prepw: fused prep (blocks 0..255) + weight conversion (blocks 256..551).
// ---------------------------------------------------------------------------
#define PPB 64
__global__ __launch_bounds__(256) void prepw_kernel(
    const float* __restrict__ img, const float* __restrict__ cloud,
    const float* __restrict__ p1w, const float* __restrict__ p1b,
    const float* __restrict__ p2w, const float* __restrict__ p2b,
    const float* __restrict__ ps1w, const float* __restrict__ ps2w,
    const float* __restrict__ c1w, const float* __restrict__ c2w,
    float4* __restrict__ pts4, ushort_t* __restrict__ cfh,
    ushort_t* __restrict__ imfh,
    ushort_t* __restrict__ w1h, ushort_t* __restrict__ w2h,
    ushort_t* __restrict__ c1h, ushort_t* __restrict__ c2h) {
  int t = threadIdx.x;
  if (blockIdx.x >= 256) {
    int e = (blockIdx.x - 256) * 256 + t;
    if (e < 32768) w1h[e] = f2bf(ps1w[e]);
    else if (e < 65536) w2h[e - 32768] = f2bf(ps2w[e - 32768]);
    else if (e < 67584) c1h[e - 65536] = f2bf(c1w[e - 65536]);
    else if (e < 75776) c2h[e - 67584] = f2bf(c2w[e - 67584]);
    return;
  }
  __shared__ alignas(16) float w2t[64 * 132];
  __shared__ alignas(16) float hs[PPB * 68];
  __shared__ alignas(16) float w1s[192];
  __shared__ alignas(16) float b1s[64];
  __shared__ alignas(16) float b2s[128];
  __shared__ float ptmp[PPB * 3];
  __shared__ float psx[PPB], psy[PPB], psz[PPB];
  int pb = blockIdx.x * PPB;

  for (int e = t; e < 128 * 64; e += 256) {
    int ch = e >> 6, k = e & 63;
    w2t[k * 132 + ch] = p2w[e];
  }
  if (t < 192) w1s[t] = p1w[t];
  if (t < 64) b1s[t] = p1b[t];
  if (t < 128) b2s[t] = p2b[t];
  if (t < PPB * 3) ptmp[t] = cloud[pb * 3 + t];
  __syncthreads();
  if (t < PPB) {
    float x = ptmp[t * 3], y = ptmp[t * 3 + 1], z = ptmp[t * 3 + 2];
    psx[t] = x; psy[t] = y; psz[t] = z;
    pts4[pb + t] = make_float4(x, y, z, x * x + y * y + z * z);
  }
  for (int e = t; e < 32 * PPB; e += 256) {
    int c = e >> 6, p = e & 63;
    imfh[(size_t)(pb + p) * 32 + c] = f2bf(img[(size_t)c * N + pb + p]);
  }
  __syncthreads();
  for (int e = t; e < PPB * 64; e += 256) {
    int pt_ = e >> 6, ch = e & 63;
    float a = b1s[ch] + psx[pt_] * w1s[ch * 3] + psy[pt_] * w1s[ch * 3 + 1] +
              psz[pt_] * w1s[ch * 3 + 2];
    hs[pt_ * 68 + ch] = lrelu(a);
  }
  __syncthreads();
  for (int e = t; e < PPB * 32; e += 256) {
    int pt_ = e >> 5, c4 = (e & 31) << 2;
    float4 acc = *(const float4*)&b2s[c4];
    const float* hrow = &hs[pt_ * 68];
    #pragma unroll
    for (int k = 0; k < 64; k += 4) {
      float4 h4 = *(const float4*)&hrow[k];
      float4 w0 = *(const float4*)&w2t[(k + 0) * 132 + c4];
      float4 w1_ = *(const float4*)&w2t[(k + 1) * 132 + c4];
      float4 w2_ = *(const float4*)&w2t[(k + 2) * 132 + c4];
      float4 w3 = *(const float4*)&w2t[(k + 3) * 132 + c4];
      acc.x = fmaf(h4.x, w0.x, fmaf(h4.y, w1_.x, fmaf(h4.z, w2_.x, fmaf(h4.w, w3.x, acc.x))));
      acc.y = fmaf(h4.x, w0.y, fmaf(h4.y, w1_.y, fmaf(h4.z, w2_.y, fmaf(h4.w, w3.y, acc.y))));
      acc.z = fmaf(h4.x, w0.z, fmaf(h4.y, w1_.z, fmaf(h4.z, w2_.z, fmaf(h4.w, w3.z, acc.z))));
      acc.w = fmaf(h4.x, w0.w, fmaf(h4.y, w1_.w, fmaf(h4.z, w2_.w, fmaf(h4.w, w3.w, acc.w))));
    }
    unsigned lo = (unsigned)f2bf(acc.x) | ((unsigned)f2bf(acc.y) << 16);
    unsigned hi = (unsigned)f2bf(acc.z) | ((unsigned)f2bf(acc.w) << 16);
    *(uint2*)&cfh[(size_t)(pb + pt_) * 128 + c4] = make_uint2(lo, hi);
  }
}

// ---------------------------------------------------------------------------
// KNN (round-6 proven shape): 4 query-waves/block, TILE=1024, 20 KB LDS,
// d2' filter with qw folded into tau; exact top-16.
// ---------------------------------------------------------------------------
__device__ __forceinline__ u64 bsort64(u64 v, int lane) {
  #pragma unroll
  for (int k = 2; k <= 64; k <<= 1) {
    #pragma unroll
    for (int j = k >> 1; j >= 1; j >>= 1) {
      u64 p = __shfl_xor(v, j);
      bool keepmin = (((lane & j) == 0) == ((lane & k) == 0));
      u64 mn = v < p ? v : p;
      u64 mx = v < p ? p : v;
      v = keepmin ? mn : mx;
    }
  }
  return v;
}

__device__ __forceinline__ u64 bclean64(u64 v, int lane) {
  #pragma unroll
  for (int j = 32; j >= 1; j >>= 1) {
    u64 p = __shfl_xor(v, j);
    u64 mn = v < p ? v : p;
    u64 mx = v < p ? p : v;
    v = ((lane & j) == 0) ? mn : mx;
  }
  return v;
}

__device__ __forceinline__ u64 compact_topk(u64* buf, int& cnt, int lane, float& tau) {
  u64 v = (lane < cnt) ? buf[lane] : ~0ULL;
  v = bsort64(v, lane);
  if (cnt > 64) {
    u64 t = (64 + lane < cnt) ? buf[64 + lane] : ~0ULL;
    t = bsort64(t, lane);
    t = __shfl_xor(t, 63);
    v = (t < v) ? t : v;
    v = bclean64(v, lane);
  }
  if (lane < 16) buf[lane] = v;
  cnt = 16;
  u64 k15 = __shfl(v, 15);
  tau = __uint_as_float((unsigned)(k15 >> 32));
  return v;
}

__device__ __forceinline__ float tadj(float tau, float qw) {
  float a = tau - qw;
  return a + fabsf(a) * 2e-7f + 1e-35f;
}

#define TILE 1024
__global__ __launch_bounds__(256) void knn_kernel(
    const float4* __restrict__ pts4, int* __restrict__ nidx, float* __restrict__ nwgt) {
  __shared__ alignas(16) float4 tile[TILE];  // 16 KB
  __shared__ u64 sbuf[4][128];               // 4 KB
  int t = threadIdx.x;
  int wv = t >> 6, lane = t & 63;
  int wid = blockIdx.x * 4 + wv;
  u64* buf = sbuf[wv];

  float4 q = pts4[wid];
  float q2x = -2.f * q.x, q2y = -2.f * q.y, q2z = -2.f * q.z, qw = q.w;
  float tau, ta;
  int cnt;

  {
    float4 c = pts4[lane];
    float d2 = fmaf(q2x, c.x, fmaf(q2y, c.y, fmaf(q2z, c.z, qw + c.w)));
    u64 v = ((u64)__float_as_uint(fmaxf(d2, 0.f)) << 32) | (unsigned)lane;
    v = bsort64(v, lane);
    if (lane < 16) buf[lane] = v;
    u64 k15 = __shfl(v, 15);
    tau = __uint_as_float((unsigned)(k15 >> 32));
    ta = tadj(tau, qw);
    cnt = 16;
  }

  for (int base = 0; base < N; base += TILE) {
    __syncthreads();
    for (int e = t; e < TILE; e += 256) tile[e] = pts4[base + e];
    __syncthreads();
    for (int s = (base == 0 ? 64 : 0); s < TILE; s += 64) {
      float4 c = tile[s + lane];
      float d2 = fmaf(q2x, c.x, fmaf(q2y, c.y, fmaf(q2z, c.z, c.w)));
      bool pass = (d2 <= ta);
      u64 mask = __ballot(pass);
      if (mask) {
        if (pass) {
          u64 key = ((u64)__float_as_uint(fmaxf(d2 + qw, 0.f)) << 32) |
                    (unsigned)(base + s + lane);
          buf[cnt + lanerank(mask)] = key;
        }
        cnt += __popcll(mask);
        if (cnt > 64) {
          compact_topk(buf, cnt, lane, tau);
          ta = tadj(tau, qw);
        }
      }
    }
  }
  u64 v = compact_topk(buf, cnt, lane, tau);

  int id = (lane < KNN) ? (int)(unsigned)(v & 0xffffffffULL) : 0;
  float4 c = pts4[id];
  float dx = q.x - c.x, dy = q.y - c.y, dz = q.z - c.z;
  float dist = sqrtf(fmaxf(dx * dx + dy * dy + dz * dz, 1e-12f));
  float md = (lane < KNN) ? dist : INFINITY;
  #pragma unroll
  for (int off = 1; off < KNN; off <<= 1) md = fminf(md, __shfl_xor(md, off));
  float e = expf(md - dist);
  float se = (lane < KNN) ? e : 0.f;
  #pragma unroll
  for (int off = 1; off < KNN; off <<= 1) se += __shfl_xor(se, off);
  if (lane < KNN) {
    nidx[wid * KNN + lane] = id;
    nwgt[wid * KNN + lane] = e / se;
  }
}

// ---------------------------------------------------------------------------
// ymlp: DEDUPLICATED dense MLPs (no gather!). y depends only on the point:
//   ycf  = psconv2(lrelu(psconv1(cf)))  + b2   [N,128]  (blocks 0..255)
//   yimg = conv2 (lrelu(conv1 (imf)))   + b2   [N,128]  (blocks 256..511)
// 64 consecutive points per block, MFMA, coalesced loads.
// ---------------------------------------------------------------------------
#define NB_LD 136
#define S1_LD 264
#define NI_LD 40
#define H1_LD 72
__global__ __launch_bounds__(256) void ymlp_kernel(
    const ushort_t* __restrict__ cfh, const ushort_t* __restrict__ imfh,
    const ushort_t* __restrict__ w1h, const float* __restrict__ b1,
    const ushort_t* __restrict__ w2h, const float* __restrict__ b2,
    const ushort_t* __restrict__ c1h, const float* __restrict__ c1b,
    const ushort_t* __restrict__ c2h, const float* __restrict__ c2b,
    ushort_t* __restrict__ ycf, ushort_t* __restrict__ yimg) {
  __shared__ ushort_t nb[64 * NB_LD];   // cf-path input / img-path input
  __shared__ ushort_t s1[64 * S1_LD];   // layer-1 activations
  int t = threadIdx.x;
  int w = t >> 6, lane = t & 63;
  int col = lane & 15, quad = lane >> 4;

  if (blockIdx.x < 256) {
    int pbase = blockIdx.x * 64;
    for (int e = t; e < 1024; e += 256) {
      int row = e >> 4, c8 = (e & 15) << 3;
      *(uint4*)&nb[row * NB_LD + c8] =
          *(const uint4*)&cfh[(size_t)(pbase + row) * 128 + c8];
    }
    __syncthreads();
    // layer1: 128 -> 256
    f32x4 acc1[4][4];
    #pragma unroll
    for (int tt = 0; tt < 4; ++tt)
      #pragma unroll
      for (int p = 0; p < 4; ++p) acc1[tt][p] = (f32x4){0.f, 0.f, 0.f, 0.f};
    for (int k0 = 0; k0 < 128; k0 += 32) {
      bf16x8 a[4];
      #pragma unroll
      for (int p = 0; p < 4; ++p)
        a[p] = *(const bf16x8*)&nb[(p * 16 + col) * NB_LD + k0 + quad * 8];
      #pragma unroll
      for (int tt = 0; tt < 4; ++tt) {
        int n = w * 64 + tt * 16 + col;
        bf16x8 b = *(const bf16x8*)&w1h[n * 128 + k0 + quad * 8];
        #pragma unroll
        for (int p = 0; p < 4; ++p)
          acc1[tt][p] = __builtin_amdgcn_mfma_f32_16x16x32_bf16(a[p], b, acc1[tt][p], 0, 0, 0);
      }
    }
    #pragma unroll
    for (int tt = 0; tt < 4; ++tt) {
      int n = w * 64 + tt * 16 + col;
      float bb = b1[n];
      #pragma unroll
      for (int p = 0; p < 4; ++p)
        #pragma unroll
        for (int r = 0; r < 4; ++r)
          s1[(p * 16 + quad * 4 + r) * S1_LD + n] = f2bf(lrelu(acc1[tt][p][r] + bb));
    }
    __syncthreads();
    // layer2: 256 -> 128, write ycf (+bias)
    f32x4 acc2[2][4];
    #pragma unroll
    for (int tt = 0; tt < 2; ++tt)
      #pragma unroll
      for (int p = 0; p < 4; ++p) acc2[tt][p] = (f32x4){0.f, 0.f, 0.f, 0.f};
    for (int k0 = 0; k0 < 256; k0 += 32) {
      bf16x8 a[4];
      #pragma unroll
      for (int p = 0; p < 4; ++p)
        a[p] = *(const bf16x8*)&s1[(p * 16 + col) * S1_LD + k0 + quad * 8];
      #pragma unroll
      for (int tt = 0; tt < 2; ++tt) {
        int n = w * 32 + tt * 16 + col;
        bf16x8 b = *(const bf16x8*)&w2h[n * 256 + k0 + quad * 8];
        #pragma unroll
        for (int p = 0; p < 4; ++p)
          acc2[tt][p] = __builtin_amdgcn_mfma_f32_16x16x32_bf16(a[p], b, acc2[tt][p], 0, 0, 0);
      }
    }
    #pragma unroll
    for (int tt = 0; tt < 2; ++tt) {
      int n = w * 32 + tt * 16 + col;
      float bb = b2[n];
      #pragma unroll
      for (int p = 0; p < 4; ++p)
        #pragma unroll
        for (int r = 0; r < 4; ++r)
          ycf[(size_t)(pbase + p * 16 + quad * 4 + r) * 128 + n] =
              f2bf(acc2[tt][p][r] + bb);
    }
  } else {
    int pbase = (blockIdx.x - 256) * 64;
    ushort_t* nbi = nb;
    ushort_t* h1 = s1;
    {
      int row = t >> 2, c8 = (t & 3) << 3;
      *(uint4*)&nbi[row * NI_LD + c8] =
          *(const uint4*)&imfh[(size_t)(pbase + row) * 32 + c8];
    }
    __syncthreads();
    // layer1: 32 -> 64
    {
      f32x4 accA[4];
      #pragma unroll
      for (int p = 0; p < 4; ++p) accA[p] = (f32x4){0.f, 0.f, 0.f, 0.f};
      int n = w * 16 + col;
      bf16x8 b = *(const bf16x8*)&c1h[n * 32 + quad * 8];
      #pragma unroll
      for (int p = 0; p < 4; ++p) {
        bf16x8 a = *(const bf16x8*)&nbi[(p * 16 + col) * NI_LD + quad * 8];
        accA[p] = __builtin_amdgcn_mfma_f32_16x16x32_bf16(a, b, accA[p], 0, 0, 0);
      }
      __syncthreads();  // nbi reads done before h1 overwrites s1 region
      float bb = c1b[n];
      #pragma unroll
      for (int p = 0; p < 4; ++p)
        #pragma unroll
        for (int r = 0; r < 4; ++r)
          h1[(p * 16 + quad * 4 + r) * H1_LD + n] = f2bf(lrelu(accA[p][r] + bb));
    }
    __syncthreads();
    // layer2: 64 -> 128, write yimg (+bias)
    f32x4 acc2[2][4];
    #pragma unroll
    for (int tt = 0; tt < 2; ++tt)
      #pragma unroll
      for (int p = 0; p < 4; ++p) acc2[tt][p] = (f32x4){0.f, 0.f, 0.f, 0.f};
    for (int k0 = 0; k0 < 64; k0 += 32) {
      bf16x8 a[4];
      #pragma unroll
      for (int p = 0; p < 4; ++p)
        a[p] = *(const bf16x8*)&h1[(p * 16 + col) * H1_LD + k0 + quad * 8];
      #pragma unroll
      for (int tt = 0; tt < 2; ++tt) {
        int n = w * 32 + tt * 16 + col;
        bf16x8 b = *(const bf16x8*)&c2h[n * 64 + k0 + quad * 8];
        #pragma unroll
        for (int p = 0; p < 4; ++p)
          acc2[tt][p] = __builtin_amdgcn_mfma_f32_16x16x32_bf16(a[p], b, acc2[tt][p], 0, 0, 0);
      }
    }
    #pragma unroll
    for (int tt = 0; tt < 2; ++tt) {
      int n = w * 32 + tt * 16 + col;
      float bb = c2b[n];
      #pragma unroll
      for (int p = 0; p < 4; ++p)
        #pragma unroll
        for (int r = 0; r < 4; ++r)
          yimg[(size_t)(pbase + p * 16 + quad * 4 + r) * 128 + n] =
              f2bf(acc2[tt][p][r] + bb);
    }
  }
}

// ---------------------------------------------------------------------------
// gmax: per point, gather 16 y-rows (each path), weighted elementwise max,
// build feat[416] in LDS, final GEMV -> out. One wave per point, NO barriers.
// lane = ksub*16 + c8: ksub in [0,4) neighbor subset, c8 in [0,16) 8-ch group.
// ---------------------------------------------------------------------------
__global__ __launch_bounds__(256) void gmax_kernel(
    const ushort_t* __restrict__ ycf, const ushort_t* __restrict__ yimg,
    const ushort_t* __restrict__ cfh, const ushort_t* __restrict__ imfh,
    const int* __restrict__ nidx, const float* __restrict__ nwgt,
    const float* __restrict__ fw, const float* __restrict__ fb,
    float* __restrict__ out) {
  __shared__ alignas(16) float feat[4][416];
  int t = threadIdx.x;
  int w = t >> 6, lane = t & 63;
  int pid = blockIdx.x * 4 + w;
  int ksub = lane >> 4, c8 = lane & 15;

  int myid = 0;
  float mywg = 0.f;
  if (lane < 16) {
    myid = nidx[pid * 16 + lane];
    mywg = nwgt[pid * 16 + lane];
  }
  // own-point features (issue early)
  float vimf = (lane < 32) ? bf2f(imfh[(size_t)pid * 32 + lane]) : 0.f;
  unsigned vcf = *(const unsigned*)&cfh[(size_t)pid * 128 + lane * 2];

  // ---- sfp: weighted max over gathered ycf rows ----
  float a0[8], a1[8];
  #pragma unroll
  for (int j = 0; j < 8; ++j) { a0[j] = -INFINITY; a1[j] = -INFINITY; }
  #pragma unroll
  for (int kk = 0; kk < 4; ++kk) {
    int k = kk * 4 + ksub;
    int id = __shfl(myid, k);
    float wg = __shfl(mywg, k);
    uint4 v = *(const uint4*)&ycf[(size_t)id * 128 + c8 * 8];
    uint4 u = *(const uint4*)&yimg[(size_t)id * 128 + c8 * 8];
    unsigned vv[4] = {v.x, v.y, v.z, v.w};
    unsigned uu[4] = {u.x, u.y, u.z, u.w};
    #pragma unroll
    for (int h = 0; h < 4; ++h) {
      a0[h * 2]     = fmaxf(a0[h * 2],     bf2f((ushort_t)(vv[h] & 0xffff)) * wg);
      a0[h * 2 + 1] = fmaxf(a0[h * 2 + 1], bf2f((ushort_t)(vv[h] >> 16)) * wg);
      a1[h * 2]     = fmaxf(a1[h * 2],     bf2f((ushort_t)(uu[h] & 0xffff)) * wg);
      a1[h * 2 + 1] = fmaxf(a1[h * 2 + 1], bf2f((ushort_t)(uu[h] >> 16)) * wg);
    }
  }
  #pragma unroll
  for (int j = 0; j < 8; ++j) {
    a0[j] = fmaxf(a0[j], __shfl_xor(a0[j], 16));
    a0[j] = fmaxf(a0[j], __shfl_xor(a0[j], 32));
    a1[j] = fmaxf(a1[j], __shfl_xor(a1[j], 16));
    a1[j] = fmaxf(a1[j], __shfl_xor(a1[j], 32));
  }
  if (lane < 16) {
    #pragma unroll
    for (int j = 0; j < 8; ++j) {
      feat[w][c8 * 8 + j] = lrelu(a0[j]);        // sfp -> [0,128)
      feat[w][160 + c8 * 8 + j] = lrelu(a1[j]);  // sf  -> [160,288)
    }
  }
  if (lane < 32) feat[w][128 + lane] = lrelu(vimf);  // imf -> [128,160)
  feat[w][288 + lane * 2] = lrelu(bf2f((ushort_t)(vcf & 0xffff)));  // cf
  feat[w][288 + lane * 2 + 1] = lrelu(bf2f((ushort_t)(vcf >> 16)));
  // same-wave LDS producer/consumer: no barrier needed

  // ---- final GEMV: out[ch][pid] ----
  int ch = lane & 31, half = lane >> 5;
  float acc = half ? 0.f : fb[ch];
  const float* wr = fw + ch * 416 + half * 208;
  const float* fr = &feat[w][half * 208];
  #pragma unroll 4
  for (int j = 0; j < 208; j += 4) {
    float4 w4 = *(const float4*)(wr + j);
    float4 f4 = *(const float4*)(fr + j);
    acc = fmaf(f4.x, w4.x, fmaf(f4.y, w4.y, fmaf(f4.z, w4.z, fmaf(f4.w, w4.w, acc))));
  }
  acc += __shfl_xor(acc, 32);
  if (lane < 32) out[(size_t)ch * N + pid] = acc;
}

// ---------------------------------------------------------------------------
extern "C" void kernel_launch(void* const* d_in, const int* in_sizes, int n_in,
                              void* d_out, int out_size, void* d_ws, size_t ws_size,
                              hipStream_t stream) {
  const float* img   = (const float*)d_in[0];
  const float* cloud = (const float*)d_in[1];
  const float* c1w   = (const float*)d_in[2];
  const float* c1b   = (const float*)d_in[3];
  const float* c2w   = (const float*)d_in[4];
  const float* c2b   = (const float*)d_in[5];
  const float* ps1w  = (const float*)d_in[6];
  const float* ps1b  = (const float*)d_in[7];
  const float* ps2w  = (const float*)d_in[8];
  const float* ps2b  = (const float*)d_in[9];
  const float* p1w   = (const float*)d_in[10];
  const float* p1b   = (const float*)d_in[11];
  const float* p2w   = (const float*)d_in[12];
  const float* p2b   = (const float*)d_in[13];
  const float* fw    = (const float*)d_in[14];
  const float* fb    = (const float*)d_in[15];
  float* out = (float*)d_out;

  char* ws = (char*)d_ws;
  float4*   pts4 = (float4*)(ws + 0);              // 256 KB
  ushort_t* cfh  = (ushort_t*)(ws + 262144);       // 4 MB
  ushort_t* imfh = (ushort_t*)(ws + 4456448);      // 1 MB
  int*      nidx = (int*)(ws + 5505024);           // 1 MB
  float*    nwgt = (float*)(ws + 6553600);         // 1 MB
  ushort_t* w1h  = (ushort_t*)(ws + 7602176);      // 64 KB
  ushort_t* w2h  = (ushort_t*)(ws + 7667712);      // 64 KB
  ushort_t* c1h  = (ushort_t*)(ws + 7733248);      // 4 KB
  ushort_t* c2h  = (ushort_t*)(ws + 7737344);      // 16 KB
  ushort_t* ycf  = (ushort_t*)(ws + 7753472);      // 4 MB
  ushort_t* yimg = (ushort_t*)(ws + 11947776);     // 4 MB

  prepw_kernel<<<552, 256, 0, stream>>>(img, cloud, p1w, p1b, p2w, p2b,
                                        ps1w, ps2w, c1w, c2w,
                                        pts4, cfh, imfh, w1h, w2h, c1h, c2h);
  knn_kernel<<<N / 4, 256, 0, stream>>>(pts4, nidx, nwgt);
  ymlp_kernel<<<512, 256, 0, stream>>>(cfh, imfh, w1h, ps1b, w2h, ps2b,
                                       c1h, c1b, c2h, c2b, ycf, yimg);
  gmax_kernel<<<N / 4, 256, 0, stream>>>(ycf, yimg, cfh, imfh, nidx, nwgt,
                                         fw, fb, out);
}

// Round 11
// 204.419 us; speedup vs baseline: 2.2478x; 1.9034x over previous
//
#include <hip/hip_runtime.h>
#include <math.h>

#define N 16384
#define KNN 16
#define G 16
#define NCELL 4096

typedef __attribute__((ext_vector_type(8))) short bf16x8;
typedef __attribute__((ext_vector_type(4))) float f32x4;
typedef unsigned short ushort_t;
typedef unsigned long long u64;

__device__ __forceinline__ float lrelu(float a) { return a > 0.f ? a : 0.01f * a; }

__device__ __forceinline__ ushort_t f2bf(float f) {
  unsigned u = __float_as_uint(f);
  u += 0x7FFF + ((u >> 16) & 1);
  return (ushort_t)(u >> 16);
}
__device__ __forceinline__ float bf2f(ushort_t h) {
  return __uint_as_float((unsigned)h << 16);
}
__device__ __forceinline__ int lanerank(u64 mask) {
  return __builtin_amdgcn_mbcnt_hi((unsigned)(mask >> 32),
         __builtin_amdgcn_mbcnt_lo((unsigned)mask, 0));
}
__device__ __forceinline__ int cellof(float x) {
  int c = (int)(x * (float)G);
  return c < 0 ? 0 : (c > G - 1 ? G - 1 : c);
}

// ---------------------------------------------------------------------------
// zcnt: zero the cell histogram
// ---------------------------------------------------------------------------
__global__ void zcnt_kernel(int* __restrict__ count) {
  count[blockIdx.x * 256 + threadIdx.x] = 0;
}

// ---------------------------------------------------------------------------
// prepw: prep (blocks 0..255, + cell histogram) + weight conv (256..603).
// fwp2 layout: element (j,ch) at (j>>2)*128 + ch*4 + (j&3), j<416.
// ---------------------------------------------------------------------------
#define PPB 64
__global__ __launch_bounds__(256) void prepw_kernel(
    const float* __restrict__ img, const float* __restrict__ cloud,
    const float* __restrict__ p1w, const float* __restrict__ p1b,
    const float* __restrict__ p2w, const float* __restrict__ p2b,
    const float* __restrict__ ps1w, const float* __restrict__ ps2w,
    const float* __restrict__ c1w, const float* __restrict__ c2w,
    const float* __restrict__ fw,
    float4* __restrict__ pts4, ushort_t* __restrict__ cfh,
    ushort_t* __restrict__ imfh,
    ushort_t* __restrict__ w1h, ushort_t* __restrict__ w2h,
    ushort_t* __restrict__ c1h, ushort_t* __restrict__ c2h,
    float* __restrict__ fwp2, int* __restrict__ count) {
  int t = threadIdx.x;
  if (blockIdx.x >= 256) {
    int e = (blockIdx.x - 256) * 256 + t;
    if (e < 32768) w1h[e] = f2bf(ps1w[e]);
    else if (e < 65536) w2h[e - 32768] = f2bf(ps2w[e - 32768]);
    else if (e < 67584) c1h[e - 65536] = f2bf(c1w[e - 65536]);
    else if (e < 75776) c2h[e - 67584] = f2bf(c2w[e - 67584]);
    else if (e < 89088) {
      int e2 = e - 75776;
      int j4 = e2 >> 7, r2 = e2 & 127;
      int ch = r2 >> 2, sub = r2 & 3;
      fwp2[e2] = fw[ch * 416 + j4 * 4 + sub];
    }
    return;
  }
  __shared__ alignas(16) float w2t[64 * 132];
  __shared__ alignas(16) float hs[PPB * 68];
  __shared__ alignas(16) float w1s[192];
  __shared__ alignas(16) float b1s[64];
  __shared__ alignas(16) float b2s[128];
  __shared__ float ptmp[PPB * 3];
  __shared__ float psx[PPB], psy[PPB], psz[PPB];
  int pb = blockIdx.x * PPB;

  for (int e = t; e < 128 * 64; e += 256) {
    int ch = e >> 6, k = e & 63;
    w2t[k * 132 + ch] = p2w[e];
  }
  if (t < 192) w1s[t] = p1w[t];
  if (t < 64) b1s[t] = p1b[t];
  if (t < 128) b2s[t] = p2b[t];
  if (t < PPB * 3) ptmp[t] = cloud[pb * 3 + t];
  __syncthreads();
  if (t < PPB) {
    float x = ptmp[t * 3], y = ptmp[t * 3 + 1], z = ptmp[t * 3 + 2];
    psx[t] = x; psy[t] = y; psz[t] = z;
    pts4[pb + t] = make_float4(x, y, z, x * x + y * y + z * z);
    int cid = ((cellof(z) << 4) | cellof(y)) << 4 | cellof(x);
    atomicAdd(&count[cid], 1);
  }
  for (int e = t; e < 32 * PPB; e += 256) {
    int c = e >> 6, p = e & 63;
    imfh[(size_t)(pb + p) * 32 + c] = f2bf(img[(size_t)c * N + pb + p]);
  }
  __syncthreads();
  for (int e = t; e < PPB * 64; e += 256) {
    int pt_ = e >> 6, ch = e & 63;
    float a = b1s[ch] + psx[pt_] * w1s[ch * 3] + psy[pt_] * w1s[ch * 3 + 1] +
              psz[pt_] * w1s[ch * 3 + 2];
    hs[pt_ * 68 + ch] = lrelu(a);
  }
  __syncthreads();
  for (int e = t; e < PPB * 32; e += 256) {
    int pt_ = e >> 5, c4 = (e & 31) << 2;
    float4 acc = *(const float4*)&b2s[c4];
    const float* hrow = &hs[pt_ * 68];
    #pragma unroll
    for (int k = 0; k < 64; k += 4) {
      float4 h4 = *(const float4*)&hrow[k];
      float4 w0 = *(const float4*)&w2t[(k + 0) * 132 + c4];
      float4 w1_ = *(const float4*)&w2t[(k + 1) * 132 + c4];
      float4 w2_ = *(const float4*)&w2t[(k + 2) * 132 + c4];
      float4 w3 = *(const float4*)&w2t[(k + 3) * 132 + c4];
      acc.x = fmaf(h4.x, w0.x, fmaf(h4.y, w1_.x, fmaf(h4.z, w2_.x, fmaf(h4.w, w3.x, acc.x))));
      acc.y = fmaf(h4.x, w0.y, fmaf(h4.y, w1_.y, fmaf(h4.z, w2_.y, fmaf(h4.w, w3.y, acc.y))));
      acc.z = fmaf(h4.x, w0.z, fmaf(h4.y, w1_.z, fmaf(h4.z, w2_.z, fmaf(h4.w, w3.z, acc.z))));
      acc.w = fmaf(h4.x, w0.w, fmaf(h4.y, w1_.w, fmaf(h4.z, w2_.w, fmaf(h4.w, w3.w, acc.w))));
    }
    unsigned lo = (unsigned)f2bf(acc.x) | ((unsigned)f2bf(acc.y) << 16);
    unsigned hi = (unsigned)f2bf(acc.z) | ((unsigned)f2bf(acc.w) << 16);
    *(uint2*)&cfh[(size_t)(pb + pt_) * 128 + c4] = make_uint2(lo, hi);
  }
}

// ---------------------------------------------------------------------------
// scan: exclusive prefix over 4096 cell counts (1 block).
// ---------------------------------------------------------------------------
__global__ __launch_bounds__(256) void scan_kernel(
    const int* __restrict__ count, int* __restrict__ cellStart,
    int* __restrict__ cellofs) {
  __shared__ int part[256];
  int t = threadIdx.x;
  int local[16];
  int s = 0;
  #pragma unroll
  for (int j = 0; j < 16; ++j) { local[j] = s; s += count[t * 16 + j]; }
  part[t] = s;
  __syncthreads();
  for (int off = 1; off < 256; off <<= 1) {
    int v = (t >= off) ? part[t - off] : 0;
    __syncthreads();
    part[t] += v;
    __syncthreads();
  }
  int base = part[t] - s;
  #pragma unroll
  for (int j = 0; j < 16; ++j) {
    int v = base + local[j];
    cellStart[t * 16 + j] = v;
    cellofs[t * 16 + j] = v;
  }
  if (t == 255) cellStart[NCELL] = part[255];
}

// ---------------------------------------------------------------------------
// scatter: points into cell-sorted order; original index packed into .w.
// ---------------------------------------------------------------------------
__global__ __launch_bounds__(256) void scatter_kernel(
    const float4* __restrict__ pts4, int* __restrict__ cellofs,
    float4* __restrict__ spts) {
  int p = blockIdx.x * 256 + threadIdx.x;
  float4 v = pts4[p];
  int cid = ((cellof(v.z) << 4) | cellof(v.y)) << 4 | cellof(v.x);
  int pos = atomicAdd(&cellofs[cid], 1);
  spts[pos] = make_float4(v.x, v.y, v.z, __int_as_float(p));
}

// ---------------------------------------------------------------------------
// KNN via grid: per query wave, scan expanding cell boxes; exact top-16.
// Ring rescan keeps tau (valid upper bound) -> no duplicates, exact set.
// ---------------------------------------------------------------------------
__device__ __forceinline__ u64 bsort64(u64 v, int lane) {
  #pragma unroll
  for (int k = 2; k <= 64; k <<= 1) {
    #pragma unroll
    for (int j = k >> 1; j >= 1; j >>= 1) {
      u64 p = __shfl_xor(v, j);
      bool keepmin = (((lane & j) == 0) == ((lane & k) == 0));
      u64 mn = v < p ? v : p;
      u64 mx = v < p ? p : v;
      v = keepmin ? mn : mx;
    }
  }
  return v;
}

__device__ __forceinline__ u64 bclean64(u64 v, int lane) {
  #pragma unroll
  for (int j = 32; j >= 1; j >>= 1) {
    u64 p = __shfl_xor(v, j);
    u64 mn = v < p ? v : p;
    u64 mx = v < p ? p : v;
    v = ((lane & j) == 0) ? mn : mx;
  }
  return v;
}

__device__ __forceinline__ u64 compact_topk(u64* buf, int& cnt, int lane, float& tau) {
  u64 v = (lane < cnt) ? buf[lane] : ~0ULL;
  v = bsort64(v, lane);
  if (cnt > 64) {
    u64 t = (64 + lane < cnt) ? buf[64 + lane] : ~0ULL;
    t = bsort64(t, lane);
    t = __shfl_xor(t, 63);
    v = (t < v) ? t : v;
    v = bclean64(v, lane);
  }
  if (lane < 16) buf[lane] = v;
  cnt = 16;
  u64 k15 = __shfl(v, 15);
  tau = __uint_as_float((unsigned)(k15 >> 32));
  if (!(tau == tau)) tau = INFINITY;  // <16 real entries -> sentinel NaN -> INF
  return v;
}

__device__ __forceinline__ float tadj(float tau, float qw) {
  float a = tau - qw;
  return a + fabsf(a) * 2e-7f + 1e-35f;
}

__global__ __launch_bounds__(256) void knng_kernel(
    const float4* __restrict__ pts4, const float4* __restrict__ spts,
    const int* __restrict__ cellStart,
    int* __restrict__ nidx, float* __restrict__ nwgt) {
  __shared__ u64 sbuf[4][128];  // 4 KB
  int t = threadIdx.x;
  int wv = t >> 6, lane = t & 63;
  int wid = blockIdx.x * 4 + wv;
  u64* buf = sbuf[wv];

  float4 q = pts4[wid];
  float q2x = -2.f * q.x, q2y = -2.f * q.y, q2z = -2.f * q.z, qw = q.w;
  int cx = cellof(q.x), cy = cellof(q.y), cz = cellof(q.z);
  float tau = INFINITY;
  u64 vres;

  for (int r = 1;; ++r) {
    int lx = max(cx - r, 0), hx = min(cx + r, G - 1);
    int ly = max(cy - r, 0), hy = min(cy + r, G - 1);
    int lz = max(cz - r, 0), hz = min(cz + r, G - 1);
    int ny = hy - ly + 1, nz = hz - lz + 1, nruns = ny * nz;
    int cnt = 0;
    float ta = tadj(tau, qw);

    for (int rb = 0; rb < nruns; rb += 64) {
      int ln = rb + lane;
      int rs = 0, rc = 0;
      if (ln < nruns) {
        int z = lz + ln / ny, y = ly + ln % ny;
        int row = ((z << 4) | y) << 4;
        rs = cellStart[row + lx];
        rc = cellStart[row + hx + 1] - rs;
      }
      int off = rc;
      #pragma unroll
      for (int d = 1; d < 64; d <<= 1) {
        int v = __shfl_up(off, d);
        if (lane >= d) off += v;
      }
      int T = __shfl(off, 63);
      off -= rc;  // exclusive prefix within this run window

      for (int cb = 0; cb < T; cb += 64) {
        int rk = cb + lane;
        // binary search: largest j with off_j <= rk (empty runs handled by ties)
        int j = 0;
        #pragma unroll
        for (int step = 32; step; step >>= 1) {
          int nj = j + step;
          int onj = __shfl(off, nj & 63);
          if (nj < 64 && onj <= rk) j = nj;
        }
        int src = __shfl(rs, j) + rk - __shfl(off, j);
        bool valid = rk < T;
        if (!valid) src = 0;
        float4 c = spts[src];
        float cw = fmaf(c.z, c.z, fmaf(c.y, c.y, c.x * c.x));
        float d2 = fmaf(q2x, c.x, fmaf(q2y, c.y, fmaf(q2z, c.z, cw)));
        bool pass = valid && (d2 <= ta);
        u64 mask = __ballot(pass);
        if (mask) {
          if (pass) {
            int oid = __float_as_int(c.w);
            u64 key = ((u64)__float_as_uint(fmaxf(d2 + qw, 0.f)) << 32) | (unsigned)oid;
            buf[cnt + lanerank(mask)] = key;
          }
          cnt += __popcll(mask);
          if (cnt > 64) {
            compact_topk(buf, cnt, lane, tau);
            ta = tadj(tau, qw);
          }
        }
      }
    }
    u64 v = compact_topk(buf, cnt, lane, tau);
    // coverage: min distance from q to any unclamped box face
    float cl = INFINITY;
    if (lx > 0)     cl = fminf(cl, q.x - (float)lx / (float)G);
    if (hx < G - 1) cl = fminf(cl, (float)(hx + 1) / (float)G - q.x);
    if (ly > 0)     cl = fminf(cl, q.y - (float)ly / (float)G);
    if (hy < G - 1) cl = fminf(cl, (float)(hy + 1) / (float)G - q.y);
    if (lz > 0)     cl = fminf(cl, q.z - (float)lz / (float)G);
    if (hz < G - 1) cl = fminf(cl, (float)(hz + 1) / (float)G - q.z);
    bool full = (lx == 0 && hx == G - 1 && ly == 0 && hy == G - 1 &&
                 lz == 0 && hz == G - 1);
    if (full || tau * 1.00002f <= cl * cl) { vres = v; break; }
    // else: expand ring; tau (upper bound on true d16) seeds the next scan
  }

  // epilogue: lanes 0-15 hold exact top-16, ascending (d2, idx)
  int id = (lane < KNN) ? (int)(unsigned)(vres & 0xffffffffULL) : 0;
  float4 c = pts4[id];
  float dx = q.x - c.x, dy = q.y - c.y, dz = q.z - c.z;
  float dist = sqrtf(fmaxf(dx * dx + dy * dy + dz * dz, 1e-12f));
  float md = (lane < KNN) ? dist : INFINITY;
  #pragma unroll
  for (int off = 1; off < KNN; off <<= 1) md = fminf(md, __shfl_xor(md, off));
  float e = expf(md - dist);
  float se = (lane < KNN) ? e : 0.f;
  #pragma unroll
  for (int off = 1; off < KNN; off <<= 1) se += __shfl_xor(se, off);
  if (lane < KNN) {
    nidx[wid * KNN + lane] = id;
    nwgt[wid * KNN + lane] = e / se;
  }
}

// ---------------------------------------------------------------------------
// ymlp: deduplicated dense MLPs (unchanged from round 10).
// ---------------------------------------------------------------------------
#define NB_LD 136
#define S1_LD 264
#define NI_LD 40
#define H1_LD 72
__global__ __launch_bounds__(256) void ymlp_kernel(
    const ushort_t* __restrict__ cfh, const ushort_t* __restrict__ imfh,
    const ushort_t* __restrict__ w1h, const float* __restrict__ b1,
    const ushort_t* __restrict__ w2h, const float* __restrict__ b2,
    const ushort_t* __restrict__ c1h, const float* __restrict__ c1b,
    const ushort_t* __restrict__ c2h, const float* __restrict__ c2b,
    ushort_t* __restrict__ ycf, ushort_t* __restrict__ yimg) {
  __shared__ ushort_t nb[64 * NB_LD];
  __shared__ ushort_t s1[64 * S1_LD];
  int t = threadIdx.x;
  int w = t >> 6, lane = t & 63;
  int col = lane & 15, quad = lane >> 4;

  if (blockIdx.x < 256) {
    int pbase = blockIdx.x * 64;
    for (int e = t; e < 1024; e += 256) {
      int row = e >> 4, c8 = (e & 15) << 3;
      *(uint4*)&nb[row * NB_LD + c8] =
          *(const uint4*)&cfh[(size_t)(pbase + row) * 128 + c8];
    }
    __syncthreads();
    f32x4 acc1[4][4];
    #pragma unroll
    for (int tt = 0; tt < 4; ++tt)
      #pragma unroll
      for (int p = 0; p < 4; ++p) acc1[tt][p] = (f32x4){0.f, 0.f, 0.f, 0.f};
    for (int k0 = 0; k0 < 128; k0 += 32) {
      bf16x8 a[4];
      #pragma unroll
      for (int p = 0; p < 4; ++p)
        a[p] = *(const bf16x8*)&nb[(p * 16 + col) * NB_LD + k0 + quad * 8];
      #pragma unroll
      for (int tt = 0; tt < 4; ++tt) {
        int n = w * 64 + tt * 16 + col;
        bf16x8 b = *(const bf16x8*)&w1h[n * 128 + k0 + quad * 8];
        #pragma unroll
        for (int p = 0; p < 4; ++p)
          acc1[tt][p] = __builtin_amdgcn_mfma_f32_16x16x32_bf16(a[p], b, acc1[tt][p], 0, 0, 0);
      }
    }
    #pragma unroll
    for (int tt = 0; tt < 4; ++tt) {
      int n = w * 64 + tt * 16 + col;
      float bb = b1[n];
      #pragma unroll
      for (int p = 0; p < 4; ++p)
        #pragma unroll
        for (int r = 0; r < 4; ++r)
          s1[(p * 16 + quad * 4 + r) * S1_LD + n] = f2bf(lrelu(acc1[tt][p][r] + bb));
    }
    __syncthreads();
    f32x4 acc2[2][4];
    #pragma unroll
    for (int tt = 0; tt < 2; ++tt)
      #pragma unroll
      for (int p = 0; p < 4; ++p) acc2[tt][p] = (f32x4){0.f, 0.f, 0.f, 0.f};
    for (int k0 = 0; k0 < 256; k0 += 32) {
      bf16x8 a[4];
      #pragma unroll
      for (int p = 0; p < 4; ++p)
        a[p] = *(const bf16x8*)&s1[(p * 16 + col) * S1_LD + k0 + quad * 8];
      #pragma unroll
      for (int tt = 0; tt < 2; ++tt) {
        int n = w * 32 + tt * 16 + col;
        bf16x8 b = *(const bf16x8*)&w2h[n * 256 + k0 + quad * 8];
        #pragma unroll
        for (int p = 0; p < 4; ++p)
          acc2[tt][p] = __builtin_amdgcn_mfma_f32_16x16x32_bf16(a[p], b, acc2[tt][p], 0, 0, 0);
      }
    }
    #pragma unroll
    for (int tt = 0; tt < 2; ++tt) {
      int n = w * 32 + tt * 16 + col;
      float bb = b2[n];
      #pragma unroll
      for (int p = 0; p < 4; ++p)
        #pragma unroll
        for (int r = 0; r < 4; ++r)
          ycf[(size_t)(pbase + p * 16 + quad * 4 + r) * 128 + n] =
              f2bf(acc2[tt][p][r] + bb);
    }
  } else {
    int pbase = (blockIdx.x - 256) * 64;
    ushort_t* nbi = nb;
    ushort_t* h1 = s1;
    {
      int row = t >> 2, c8 = (t & 3) << 3;
      *(uint4*)&nbi[row * NI_LD + c8] =
          *(const uint4*)&imfh[(size_t)(pbase + row) * 32 + c8];
    }
    __syncthreads();
    {
      f32x4 accA[4];
      #pragma unroll
      for (int p = 0; p < 4; ++p) accA[p] = (f32x4){0.f, 0.f, 0.f, 0.f};
      int n = w * 16 + col;
      bf16x8 b = *(const bf16x8*)&c1h[n * 32 + quad * 8];
      #pragma unroll
      for (int p = 0; p < 4; ++p) {
        bf16x8 a = *(const bf16x8*)&nbi[(p * 16 + col) * NI_LD + quad * 8];
        accA[p] = __builtin_amdgcn_mfma_f32_16x16x32_bf16(a, b, accA[p], 0, 0, 0);
      }
      __syncthreads();
      float bb = c1b[n];
      #pragma unroll
      for (int p = 0; p < 4; ++p)
        #pragma unroll
        for (int r = 0; r < 4; ++r)
          h1[(p * 16 + quad * 4 + r) * H1_LD + n] = f2bf(lrelu(accA[p][r] + bb));
    }
    __syncthreads();
    f32x4 acc2[2][4];
    #pragma unroll
    for (int tt = 0; tt < 2; ++tt)
      #pragma unroll
      for (int p = 0; p < 4; ++p) acc2[tt][p] = (f32x4){0.f, 0.f, 0.f, 0.f};
    for (int k0 = 0; k0 < 64; k0 += 32) {
      bf16x8 a[4];
      #pragma unroll
      for (int p = 0; p < 4; ++p)
        a[p] = *(const bf16x8*)&h1[(p * 16 + col) * H1_LD + k0 + quad * 8];
      #pragma unroll
      for (int tt = 0; tt < 2; ++tt) {
        int n = w * 32 + tt * 16 + col;
        bf16x8 b = *(const bf16x8*)&c2h[n * 64 + k0 + quad * 8];
        #pragma unroll
        for (int p = 0; p < 4; ++p)
          acc2[tt][p] = __builtin_amdgcn_mfma_f32_16x16x32_bf16(a[p], b, acc2[tt][p], 0, 0, 0);
      }
    }
    #pragma unroll
    for (int tt = 0; tt < 2; ++tt) {
      int n = w * 32 + tt * 16 + col;
      float bb = c2b[n];
      #pragma unroll
      for (int p = 0; p < 4; ++p)
        #pragma unroll
        for (int r = 0; r < 4; ++r)
          yimg[(size_t)(pbase + p * 16 + quad * 4 + r) * 128 + n] =
              f2bf(acc2[tt][p][r] + bb);
    }
  }
}

// ---------------------------------------------------------------------------
// gmax: gather-max + feat + final GEMV (coalesced fwp2 weights).
// ---------------------------------------------------------------------------
__global__ __launch_bounds__(256) void gmax_kernel(
    const ushort_t* __restrict__ ycf, const ushort_t* __restrict__ yimg,
    const ushort_t* __restrict__ cfh, const ushort_t* __restrict__ imfh,
    const int* __restrict__ nidx, const float* __restrict__ nwgt,
    const float* __restrict__ fwp2, const float* __restrict__ fb,
    float* __restrict__ out) {
  __shared__ alignas(16) float feat[4][416];
  int t = threadIdx.x;
  int w = t >> 6, lane = t & 63;
  int pid = blockIdx.x * 4 + w;
  int ksub = lane >> 4, c8 = lane & 15;

  int myid = 0;
  float mywg = 0.f;
  if (lane < 16) {
    myid = nidx[pid * 16 + lane];
    mywg = nwgt[pid * 16 + lane];
  }
  float vimf = (lane < 32) ? bf2f(imfh[(size_t)pid * 32 + lane]) : 0.f;
  unsigned vcf = *(const unsigned*)&cfh[(size_t)pid * 128 + lane * 2];

  float a0[8], a1[8];
  #pragma unroll
  for (int j = 0; j < 8; ++j) { a0[j] = -INFINITY; a1[j] = -INFINITY; }
  #pragma unroll
  for (int kk = 0; kk < 4; ++kk) {
    int k = kk * 4 + ksub;
    int id = __shfl(myid, k);
    float wg = __shfl(mywg, k);
    uint4 v = *(const uint4*)&ycf[(size_t)id * 128 + c8 * 8];
    uint4 u = *(const uint4*)&yimg[(size_t)id * 128 + c8 * 8];
    unsigned vv[4] = {v.x, v.y, v.z, v.w};
    unsigned uu[4] = {u.x, u.y, u.z, u.w};
    #pragma unroll
    for (int h = 0; h < 4; ++h) {
      a0[h * 2]     = fmaxf(a0[h * 2],     bf2f((ushort_t)(vv[h] & 0xffff)) * wg);
      a0[h * 2 + 1] = fmaxf(a0[h * 2 + 1], bf2f((ushort_t)(vv[h] >> 16)) * wg);
      a1[h * 2]     = fmaxf(a1[h * 2],     bf2f((ushort_t)(uu[h] & 0xffff)) * wg);
      a1[h * 2 + 1] = fmaxf(a1[h * 2 + 1], bf2f((ushort_t)(uu[h] >> 16)) * wg);
    }
  }
  #pragma unroll
  for (int j = 0; j < 8; ++j) {
    a0[j] = fmaxf(a0[j], __shfl_xor(a0[j], 16));
    a0[j] = fmaxf(a0[j], __shfl_xor(a0[j], 32));
    a1[j] = fmaxf(a1[j], __shfl_xor(a1[j], 16));
    a1[j] = fmaxf(a1[j], __shfl_xor(a1[j], 32));
  }
  if (lane < 16) {
    #pragma unroll
    for (int j = 0; j < 8; ++j) {
      feat[w][c8 * 8 + j] = lrelu(a0[j]);
      feat[w][160 + c8 * 8 + j] = lrelu(a1[j]);
    }
  }
  if (lane < 32) feat[w][128 + lane] = lrelu(vimf);
  feat[w][288 + lane * 2] = lrelu(bf2f((ushort_t)(vcf & 0xffff)));
  feat[w][288 + lane * 2 + 1] = lrelu(bf2f((ushort_t)(vcf >> 16)));
  // same-wave LDS producer/consumer: no barrier needed

  int ch = lane & 31, half = lane >> 5;
  float acc = half ? 0.f : fb[ch];
  const float* wr = fwp2 + (half * 52) * 128 + ch * 4;
  const float* fr = &feat[w][half * 208];
  #pragma unroll 4
  for (int j4 = 0; j4 < 52; ++j4) {
    float4 w4 = *(const float4*)(wr + j4 * 128);
    float4 f4 = *(const float4*)(fr + j4 * 4);
    acc = fmaf(f4.x, w4.x, fmaf(f4.y, w4.y, fmaf(f4.z, w4.z, fmaf(f4.w, w4.w, acc))));
  }
  acc += __shfl_xor(acc, 32);
  if (lane < 32) out[(size_t)ch * N + pid] = acc;
}

// ---------------------------------------------------------------------------
extern "C" void kernel_launch(void* const* d_in, const int* in_sizes, int n_in,
                              void* d_out, int out_size, void* d_ws, size_t ws_size,
                              hipStream_t stream) {
  const float* img   = (const float*)d_in[0];
  const float* cloud = (const float*)d_in[1];
  const float* c1w   = (const float*)d_in[2];
  const float* c1b   = (const float*)d_in[3];
  const float* c2w   = (const float*)d_in[4];
  const float* c2b   = (const float*)d_in[5];
  const float* ps1w  = (const float*)d_in[6];
  const float* ps1b  = (const float*)d_in[7];
  const float* ps2w  = (const float*)d_in[8];
  const float* ps2b  = (const float*)d_in[9];
  const float* p1w   = (const float*)d_in[10];
  const float* p1b   = (const float*)d_in[11];
  const float* p2w   = (const float*)d_in[12];
  const float* p2b   = (const float*)d_in[13];
  const float* fw    = (const float*)d_in[14];
  const float* fb    = (const float*)d_in[15];
  float* out = (float*)d_out;

  char* ws = (char*)d_ws;
  float4*   pts4  = (float4*)(ws + 0);             // 256 KB
  ushort_t* cfh   = (ushort_t*)(ws + 262144);      // 4 MB
  ushort_t* imfh  = (ushort_t*)(ws + 4456448);     // 1 MB
  int*      nidx  = (int*)(ws + 5505024);          // 1 MB
  float*    nwgt  = (float*)(ws + 6553600);        // 1 MB
  ushort_t* w1h   = (ushort_t*)(ws + 7602176);     // 64 KB
  ushort_t* w2h   = (ushort_t*)(ws + 7667712);     // 64 KB
  ushort_t* c1h   = (ushort_t*)(ws + 7733248);     // 4 KB
  ushort_t* c2h   = (ushort_t*)(ws + 7737344);     // 16 KB
  ushort_t* ycf   = (ushort_t*)(ws + 7753472);     // 4 MB
  ushort_t* yimg  = (ushort_t*)(ws + 11947776);    // 4 MB
  float4*   spts  = (float4*)(ws + 16142080);      // 256 KB
  int*      cellStart = (int*)(ws + 16404224);     // 32 KB (4097 used)
  int*      cellofs   = (int*)(ws + 16436992);     // 16 KB
  int*      count     = (int*)(ws + 16453376);     // 16 KB
  float*    fwp2      = (float*)(ws + 16469760);   // 53 KB

  zcnt_kernel<<<16, 256, 0, stream>>>(count);
  prepw_kernel<<<604, 256, 0, stream>>>(img, cloud, p1w, p1b, p2w, p2b,
                                        ps1w, ps2w, c1w, c2w, fw,
                                        pts4, cfh, imfh, w1h, w2h, c1h, c2h,
                                        fwp2, count);
  scan_kernel<<<1, 256, 0, stream>>>(count, cellStart, cellofs);
  scatter_kernel<<<64, 256, 0, stream>>>(pts4, cellofs, spts);
  knng_kernel<<<N / 4, 256, 0, stream>>>(pts4, spts, cellStart, nidx, nwgt);
  ymlp_kernel<<<512, 256, 0, stream>>>(cfh, imfh, w1h, ps1b, w2h, ps2b,
                                       c1h, c1b, c2h, c2b, ycf, yimg);
  gmax_kernel<<<N / 4, 256, 0, stream>>>(ycf, yimg, cfh, imfh, nidx, nwgt,
                                         fwp2, fb, out);
}

// Round 12
// 190.212 us; speedup vs baseline: 2.4156x; 1.0747x over previous
//
#include <hip/hip_runtime.h>
#include <math.h>

#define N 16384
#define KNN 16
#define G 16
#define NCELL 4096

typedef __attribute__((ext_vector_type(8))) short bf16x8;
typedef __attribute__((ext_vector_type(4))) float f32x4;
typedef unsigned short ushort_t;
typedef unsigned long long u64;

__device__ __forceinline__ float lrelu(float a) { return a > 0.f ? a : 0.01f * a; }

__device__ __forceinline__ ushort_t f2bf(float f) {
  unsigned u = __float_as_uint(f);
  u += 0x7FFF + ((u >> 16) & 1);
  return (ushort_t)(u >> 16);
}
__device__ __forceinline__ float bf2f(ushort_t h) {
  return __uint_as_float((unsigned)h << 16);
}
__device__ __forceinline__ int lanerank(u64 mask) {
  return __builtin_amdgcn_mbcnt_hi((unsigned)(mask >> 32),
         __builtin_amdgcn_mbcnt_lo((unsigned)mask, 0));
}
__device__ __forceinline__ int cellof(float x) {
  int c = (int)(x * (float)G);
  return c < 0 ? 0 : (c > G - 1 ? G - 1 : c);
}

// ---------------------------------------------------------------------------
// prepw: prep (blocks 0..255, + cell histogram) + weight conv (256..603).
// fwp2 layout: element (j,ch) at (j>>2)*128 + ch*4 + (j&3), j<416.
// ---------------------------------------------------------------------------
#define PPB 64
__global__ __launch_bounds__(256) void prepw_kernel(
    const float* __restrict__ img, const float* __restrict__ cloud,
    const float* __restrict__ p1w, const float* __restrict__ p1b,
    const float* __restrict__ p2w, const float* __restrict__ p2b,
    const float* __restrict__ ps1w, const float* __restrict__ ps2w,
    const float* __restrict__ c1w, const float* __restrict__ c2w,
    const float* __restrict__ fw,
    float4* __restrict__ pts4, ushort_t* __restrict__ cfh,
    ushort_t* __restrict__ imfh,
    ushort_t* __restrict__ w1h, ushort_t* __restrict__ w2h,
    ushort_t* __restrict__ c1h, ushort_t* __restrict__ c2h,
    float* __restrict__ fwp2, int* __restrict__ count) {
  int t = threadIdx.x;
  if (blockIdx.x >= 256) {
    int e = (blockIdx.x - 256) * 256 + t;
    if (e < 32768) w1h[e] = f2bf(ps1w[e]);
    else if (e < 65536) w2h[e - 32768] = f2bf(ps2w[e - 32768]);
    else if (e < 67584) c1h[e - 65536] = f2bf(c1w[e - 65536]);
    else if (e < 75776) c2h[e - 67584] = f2bf(c2w[e - 67584]);
    else if (e < 89088) {
      int e2 = e - 75776;
      int j4 = e2 >> 7, r2 = e2 & 127;
      int ch = r2 >> 2, sub = r2 & 3;
      fwp2[e2] = fw[ch * 416 + j4 * 4 + sub];
    }
    return;
  }
  __shared__ alignas(16) float w2t[64 * 132];
  __shared__ alignas(16) float hs[PPB * 68];
  __shared__ alignas(16) float w1s[192];
  __shared__ alignas(16) float b1s[64];
  __shared__ alignas(16) float b2s[128];
  __shared__ float ptmp[PPB * 3];
  __shared__ float psx[PPB], psy[PPB], psz[PPB];
  int pb = blockIdx.x * PPB;

  for (int e = t; e < 128 * 64; e += 256) {
    int ch = e >> 6, k = e & 63;
    w2t[k * 132 + ch] = p2w[e];
  }
  if (t < 192) w1s[t] = p1w[t];
  if (t < 64) b1s[t] = p1b[t];
  if (t < 128) b2s[t] = p2b[t];
  if (t < PPB * 3) ptmp[t] = cloud[pb * 3 + t];
  __syncthreads();
  if (t < PPB) {
    float x = ptmp[t * 3], y = ptmp[t * 3 + 1], z = ptmp[t * 3 + 2];
    psx[t] = x; psy[t] = y; psz[t] = z;
    pts4[pb + t] = make_float4(x, y, z, x * x + y * y + z * z);
    int cid = ((cellof(z) << 4) | cellof(y)) << 4 | cellof(x);
    atomicAdd(&count[cid], 1);
  }
  for (int e = t; e < 32 * PPB; e += 256) {
    int c = e >> 6, p = e & 63;
    imfh[(size_t)(pb + p) * 32 + c] = f2bf(img[(size_t)c * N + pb + p]);
  }
  __syncthreads();
  for (int e = t; e < PPB * 64; e += 256) {
    int pt_ = e >> 6, ch = e & 63;
    float a = b1s[ch] + psx[pt_] * w1s[ch * 3] + psy[pt_] * w1s[ch * 3 + 1] +
              psz[pt_] * w1s[ch * 3 + 2];
    hs[pt_ * 68 + ch] = lrelu(a);
  }
  __syncthreads();
  for (int e = t; e < PPB * 32; e += 256) {
    int pt_ = e >> 5, c4 = (e & 31) << 2;
    float4 acc = *(const float4*)&b2s[c4];
    const float* hrow = &hs[pt_ * 68];
    #pragma unroll
    for (int k = 0; k < 64; k += 4) {
      float4 h4 = *(const float4*)&hrow[k];
      float4 w0 = *(const float4*)&w2t[(k + 0) * 132 + c4];
      float4 w1_ = *(const float4*)&w2t[(k + 1) * 132 + c4];
      float4 w2_ = *(const float4*)&w2t[(k + 2) * 132 + c4];
      float4 w3 = *(const float4*)&w2t[(k + 3) * 132 + c4];
      acc.x = fmaf(h4.x, w0.x, fmaf(h4.y, w1_.x, fmaf(h4.z, w2_.x, fmaf(h4.w, w3.x, acc.x))));
      acc.y = fmaf(h4.x, w0.y, fmaf(h4.y, w1_.y, fmaf(h4.z, w2_.y, fmaf(h4.w, w3.y, acc.y))));
      acc.z = fmaf(h4.x, w0.z, fmaf(h4.y, w1_.z, fmaf(h4.z, w2_.z, fmaf(h4.w, w3.z, acc.z))));
      acc.w = fmaf(h4.x, w0.w, fmaf(h4.y, w1_.w, fmaf(h4.z, w2_.w, fmaf(h4.w, w3.w, acc.w))));
    }
    unsigned lo = (unsigned)f2bf(acc.x) | ((unsigned)f2bf(acc.y) << 16);
    unsigned hi = (unsigned)f2bf(acc.z) | ((unsigned)f2bf(acc.w) << 16);
    *(uint2*)&cfh[(size_t)(pb + pt_) * 128 + c4] = make_uint2(lo, hi);
  }
}

// ---------------------------------------------------------------------------
// scan: exclusive prefix over 4096 cell counts (1 block).
// ---------------------------------------------------------------------------
__global__ __launch_bounds__(256) void scan_kernel(
    const int* __restrict__ count, int* __restrict__ cellStart,
    int* __restrict__ cellofs) {
  __shared__ int part[256];
  int t = threadIdx.x;
  int local[16];
  int s = 0;
  #pragma unroll
  for (int j = 0; j < 16; ++j) { local[j] = s; s += count[t * 16 + j]; }
  part[t] = s;
  __syncthreads();
  for (int off = 1; off < 256; off <<= 1) {
    int v = (t >= off) ? part[t - off] : 0;
    __syncthreads();
    part[t] += v;
    __syncthreads();
  }
  int base = part[t] - s;
  #pragma unroll
  for (int j = 0; j < 16; ++j) {
    int v = base + local[j];
    cellStart[t * 16 + j] = v;
    cellofs[t * 16 + j] = v;
  }
  if (t == 255) cellStart[NCELL] = part[255];
}

// ---------------------------------------------------------------------------
// scatter: points into cell-sorted order; original index packed into .w.
// ---------------------------------------------------------------------------
__global__ __launch_bounds__(256) void scatter_kernel(
    const float4* __restrict__ pts4, int* __restrict__ cellofs,
    float4* __restrict__ spts) {
  int p = blockIdx.x * 256 + threadIdx.x;
  float4 v = pts4[p];
  int cid = ((cellof(v.z) << 4) | cellof(v.y)) << 4 | cellof(v.x);
  int pos = atomicAdd(&cellofs[cid], 1);
  spts[pos] = make_float4(v.x, v.y, v.z, __int_as_float(p));
}

// ---------------------------------------------------------------------------
// ymlp: deduplicated dense MLPs (unchanged).
// ---------------------------------------------------------------------------
#define NB_LD 136
#define S1_LD 264
#define NI_LD 40
#define H1_LD 72
__global__ __launch_bounds__(256) void ymlp_kernel(
    const ushort_t* __restrict__ cfh, const ushort_t* __restrict__ imfh,
    const ushort_t* __restrict__ w1h, const float* __restrict__ b1,
    const ushort_t* __restrict__ w2h, const float* __restrict__ b2,
    const ushort_t* __restrict__ c1h, const float* __restrict__ c1b,
    const ushort_t* __restrict__ c2h, const float* __restrict__ c2b,
    ushort_t* __restrict__ ycf, ushort_t* __restrict__ yimg) {
  __shared__ ushort_t nb[64 * NB_LD];
  __shared__ ushort_t s1[64 * S1_LD];
  int t = threadIdx.x;
  int w = t >> 6, lane = t & 63;
  int col = lane & 15, quad = lane >> 4;

  if (blockIdx.x < 256) {
    int pbase = blockIdx.x * 64;
    for (int e = t; e < 1024; e += 256) {
      int row = e >> 4, c8 = (e & 15) << 3;
      *(uint4*)&nb[row * NB_LD + c8] =
          *(const uint4*)&cfh[(size_t)(pbase + row) * 128 + c8];
    }
    __syncthreads();
    f32x4 acc1[4][4];
    #pragma unroll
    for (int tt = 0; tt < 4; ++tt)
      #pragma unroll
      for (int p = 0; p < 4; ++p) acc1[tt][p] = (f32x4){0.f, 0.f, 0.f, 0.f};
    for (int k0 = 0; k0 < 128; k0 += 32) {
      bf16x8 a[4];
      #pragma unroll
      for (int p = 0; p < 4; ++p)
        a[p] = *(const bf16x8*)&nb[(p * 16 + col) * NB_LD + k0 + quad * 8];
      #pragma unroll
      for (int tt = 0; tt < 4; ++tt) {
        int n = w * 64 + tt * 16 + col;
        bf16x8 b = *(const bf16x8*)&w1h[n * 128 + k0 + quad * 8];
        #pragma unroll
        for (int p = 0; p < 4; ++p)
          acc1[tt][p] = __builtin_amdgcn_mfma_f32_16x16x32_bf16(a[p], b, acc1[tt][p], 0, 0, 0);
      }
    }
    #pragma unroll
    for (int tt = 0; tt < 4; ++tt) {
      int n = w * 64 + tt * 16 + col;
      float bb = b1[n];
      #pragma unroll
      for (int p = 0; p < 4; ++p)
        #pragma unroll
        for (int r = 0; r < 4; ++r)
          s1[(p * 16 + quad * 4 + r) * S1_LD + n] = f2bf(lrelu(acc1[tt][p][r] + bb));
    }
    __syncthreads();
    f32x4 acc2[2][4];
    #pragma unroll
    for (int tt = 0; tt < 2; ++tt)
      #pragma unroll
      for (int p = 0; p < 4; ++p) acc2[tt][p] = (f32x4){0.f, 0.f, 0.f, 0.f};
    for (int k0 = 0; k0 < 256; k0 += 32) {
      bf16x8 a[4];
      #pragma unroll
      for (int p = 0; p < 4; ++p)
        a[p] = *(const bf16x8*)&s1[(p * 16 + col) * S1_LD + k0 + quad * 8];
      #pragma unroll
      for (int tt = 0; tt < 2; ++tt) {
        int n = w * 32 + tt * 16 + col;
        bf16x8 b = *(const bf16x8*)&w2h[n * 256 + k0 + quad * 8];
        #pragma unroll
        for (int p = 0; p < 4; ++p)
          acc2[tt][p] = __builtin_amdgcn_mfma_f32_16x16x32_bf16(a[p], b, acc2[tt][p], 0, 0, 0);
      }
    }
    #pragma unroll
    for (int tt = 0; tt < 2; ++tt) {
      int n = w * 32 + tt * 16 + col;
      float bb = b2[n];
      #pragma unroll
      for (int p = 0; p < 4; ++p)
        #pragma unroll
        for (int r = 0; r < 4; ++r)
          ycf[(size_t)(pbase + p * 16 + quad * 4 + r) * 128 + n] =
              f2bf(acc2[tt][p][r] + bb);
    }
  } else {
    int pbase = (blockIdx.x - 256) * 64;
    ushort_t* nbi = nb;
    ushort_t* h1 = s1;
    {
      int row = t >> 2, c8 = (t & 3) << 3;
      *(uint4*)&nbi[row * NI_LD + c8] =
          *(const uint4*)&imfh[(size_t)(pbase + row) * 32 + c8];
    }
    __syncthreads();
    {
      f32x4 accA[4];
      #pragma unroll
      for (int p = 0; p < 4; ++p) accA[p] = (f32x4){0.f, 0.f, 0.f, 0.f};
      int n = w * 16 + col;
      bf16x8 b = *(const bf16x8*)&c1h[n * 32 + quad * 8];
      #pragma unroll
      for (int p = 0; p < 4; ++p) {
        bf16x8 a = *(const bf16x8*)&nbi[(p * 16 + col) * NI_LD + quad * 8];
        accA[p] = __builtin_amdgcn_mfma_f32_16x16x32_bf16(a, b, accA[p], 0, 0, 0);
      }
      __syncthreads();
      float bb = c1b[n];
      #pragma unroll
      for (int p = 0; p < 4; ++p)
        #pragma unroll
        for (int r = 0; r < 4; ++r)
          h1[(p * 16 + quad * 4 + r) * H1_LD + n] = f2bf(lrelu(accA[p][r] + bb));
    }
    __syncthreads();
    f32x4 acc2[2][4];
    #pragma unroll
    for (int tt = 0; tt < 2; ++tt)
      #pragma unroll
      for (int p = 0; p < 4; ++p) acc2[tt][p] = (f32x4){0.f, 0.f, 0.f, 0.f};
    for (int k0 = 0; k0 < 64; k0 += 32) {
      bf16x8 a[4];
      #pragma unroll
      for (int p = 0; p < 4; ++p)
        a[p] = *(const bf16x8*)&h1[(p * 16 + col) * H1_LD + k0 + quad * 8];
      #pragma unroll
      for (int tt = 0; tt < 2; ++tt) {
        int n = w * 32 + tt * 16 + col;
        bf16x8 b = *(const bf16x8*)&c2h[n * 64 + k0 + quad * 8];
        #pragma unroll
        for (int p = 0; p < 4; ++p)
          acc2[tt][p] = __builtin_amdgcn_mfma_f32_16x16x32_bf16(a[p], b, acc2[tt][p], 0, 0, 0);
      }
    }
    #pragma unroll
    for (int tt = 0; tt < 2; ++tt) {
      int n = w * 32 + tt * 16 + col;
      float bb = c2b[n];
      #pragma unroll
      for (int p = 0; p < 4; ++p)
        #pragma unroll
        for (int r = 0; r < 4; ++r)
          yimg[(size_t)(pbase + p * 16 + quad * 4 + r) * 128 + n] =
              f2bf(acc2[tt][p][r] + bb);
    }
  }
}

// ---------------------------------------------------------------------------
// knng_gmax: grid KNN (exact top-16) FUSED with gather-max + feat + final
// GEMV. One wave per query; fast queries proceed to gather/GEMV while slow
// ones scan -> tail overlap. nidx/nwgt never materialized.
// ---------------------------------------------------------------------------
__device__ __forceinline__ u64 bsort64(u64 v, int lane) {
  #pragma unroll
  for (int k = 2; k <= 64; k <<= 1) {
    #pragma unroll
    for (int j = k >> 1; j >= 1; j >>= 1) {
      u64 p = __shfl_xor(v, j);
      bool keepmin = (((lane & j) == 0) == ((lane & k) == 0));
      u64 mn = v < p ? v : p;
      u64 mx = v < p ? p : v;
      v = keepmin ? mn : mx;
    }
  }
  return v;
}

__device__ __forceinline__ u64 bclean64(u64 v, int lane) {
  #pragma unroll
  for (int j = 32; j >= 1; j >>= 1) {
    u64 p = __shfl_xor(v, j);
    u64 mn = v < p ? v : p;
    u64 mx = v < p ? p : v;
    v = ((lane & j) == 0) ? mn : mx;
  }
  return v;
}

__device__ __forceinline__ u64 compact_topk(u64* buf, int& cnt, int lane, float& tau) {
  u64 v = (lane < cnt) ? buf[lane] : ~0ULL;
  v = bsort64(v, lane);
  if (cnt > 64) {
    u64 t = (64 + lane < cnt) ? buf[64 + lane] : ~0ULL;
    t = bsort64(t, lane);
    t = __shfl_xor(t, 63);
    v = (t < v) ? t : v;
    v = bclean64(v, lane);
  }
  if (lane < 16) buf[lane] = v;
  cnt = 16;
  u64 k15 = __shfl(v, 15);
  tau = __uint_as_float((unsigned)(k15 >> 32));
  if (!(tau == tau)) tau = INFINITY;
  return v;
}

__device__ __forceinline__ float tadj(float tau, float qw) {
  float a = tau - qw;
  return a + fabsf(a) * 2e-7f + 1e-35f;
}

__global__ __launch_bounds__(256) void knng_kernel(
    const float4* __restrict__ pts4, const float4* __restrict__ spts,
    const int* __restrict__ cellStart,
    const ushort_t* __restrict__ ycf, const ushort_t* __restrict__ yimg,
    const ushort_t* __restrict__ cfh, const ushort_t* __restrict__ imfh,
    const float* __restrict__ fwp2, const float* __restrict__ fb,
    float* __restrict__ out) {
  __shared__ u64 sbuf[4][128];                 // 4 KB
  __shared__ alignas(16) float feat[4][416];   // 6.5 KB
  int t = threadIdx.x;
  int wv = t >> 6, lane = t & 63;
  int wid = blockIdx.x * 4 + wv;
  u64* buf = sbuf[wv];

  float4 q = pts4[wid];
  float q2x = -2.f * q.x, q2y = -2.f * q.y, q2z = -2.f * q.z, qw = q.w;
  int cx = cellof(q.x), cy = cellof(q.y), cz = cellof(q.z);
  float tau = INFINITY;
  u64 vres;

  for (int r = 1;; ++r) {
    int lx = max(cx - r, 0), hx = min(cx + r, G - 1);
    int ly = max(cy - r, 0), hy = min(cy + r, G - 1);
    int lz = max(cz - r, 0), hz = min(cz + r, G - 1);
    int ny = hy - ly + 1, nz = hz - lz + 1, nruns = ny * nz;
    int cnt = 0;
    float ta = tadj(tau, qw);

    for (int rb = 0; rb < nruns; rb += 64) {
      int ln = rb + lane;
      int rs = 0, rc = 0;
      if (ln < nruns) {
        int z = lz + ln / ny, y = ly + ln % ny;
        int row = ((z << 4) | y) << 4;
        rs = cellStart[row + lx];
        rc = cellStart[row + hx + 1] - rs;
      }
      int off = rc;
      #pragma unroll
      for (int d = 1; d < 64; d <<= 1) {
        int v = __shfl_up(off, d);
        if (lane >= d) off += v;
      }
      int T = __shfl(off, 63);
      off -= rc;

      for (int cb = 0; cb < T; cb += 64) {
        int rk = cb + lane;
        int j = 0;
        #pragma unroll
        for (int step = 32; step; step >>= 1) {
          int nj = j + step;
          int onj = __shfl(off, nj & 63);
          if (nj < 64 && onj <= rk) j = nj;
        }
        int src = __shfl(rs, j) + rk - __shfl(off, j);
        bool valid = rk < T;
        if (!valid) src = 0;
        float4 c = spts[src];
        float cw = fmaf(c.z, c.z, fmaf(c.y, c.y, c.x * c.x));
        float d2 = fmaf(q2x, c.x, fmaf(q2y, c.y, fmaf(q2z, c.z, cw)));
        bool pass = valid && (d2 <= ta);
        u64 mask = __ballot(pass);
        if (mask) {
          if (pass) {
            int oid = __float_as_int(c.w);
            u64 key = ((u64)__float_as_uint(fmaxf(d2 + qw, 0.f)) << 32) | (unsigned)oid;
            buf[cnt + lanerank(mask)] = key;
          }
          cnt += __popcll(mask);
          if (cnt > 64) {
            compact_topk(buf, cnt, lane, tau);
            ta = tadj(tau, qw);
          }
        }
      }
    }
    u64 v = compact_topk(buf, cnt, lane, tau);
    float cl = INFINITY;
    if (lx > 0)     cl = fminf(cl, q.x - (float)lx / (float)G);
    if (hx < G - 1) cl = fminf(cl, (float)(hx + 1) / (float)G - q.x);
    if (ly > 0)     cl = fminf(cl, q.y - (float)ly / (float)G);
    if (hy < G - 1) cl = fminf(cl, (float)(hy + 1) / (float)G - q.y);
    if (lz > 0)     cl = fminf(cl, q.z - (float)lz / (float)G);
    if (hz < G - 1) cl = fminf(cl, (float)(hz + 1) / (float)G - q.z);
    bool full = (lx == 0 && hx == G - 1 && ly == 0 && hy == G - 1 &&
                 lz == 0 && hz == G - 1);
    if (full || tau * 1.00002f <= cl * cl) { vres = v; break; }
  }

  // ---- softmax weights (lanes 0-15 hold exact top-16, ascending) ----
  int myid = (lane < KNN) ? (int)(unsigned)(vres & 0xffffffffULL) : 0;
  float mywg = 0.f;
  {
    float4 c = pts4[myid];
    float dx = q.x - c.x, dy = q.y - c.y, dz = q.z - c.z;
    float dist = sqrtf(fmaxf(dx * dx + dy * dy + dz * dz, 1e-12f));
    float md = (lane < KNN) ? dist : INFINITY;
    #pragma unroll
    for (int off = 1; off < KNN; off <<= 1) md = fminf(md, __shfl_xor(md, off));
    float e = expf(md - dist);
    float se = (lane < KNN) ? e : 0.f;
    #pragma unroll
    for (int off = 1; off < KNN; off <<= 1) se += __shfl_xor(se, off);
    mywg = e / se;  // valid on lanes < 16
  }

  // ---- gather-max over ycf / yimg rows ----
  int pid = wid;
  int ksub = lane >> 4, c8 = lane & 15;
  float vimf = (lane < 32) ? bf2f(imfh[(size_t)pid * 32 + lane]) : 0.f;
  unsigned vcf = *(const unsigned*)&cfh[(size_t)pid * 128 + lane * 2];

  float a0[8], a1[8];
  #pragma unroll
  for (int j = 0; j < 8; ++j) { a0[j] = -INFINITY; a1[j] = -INFINITY; }
  #pragma unroll
  for (int kk = 0; kk < 4; ++kk) {
    int k = kk * 4 + ksub;
    int id = __shfl(myid, k);
    float wg = __shfl(mywg, k);
    uint4 v = *(const uint4*)&ycf[(size_t)id * 128 + c8 * 8];
    uint4 u = *(const uint4*)&yimg[(size_t)id * 128 + c8 * 8];
    unsigned vv[4] = {v.x, v.y, v.z, v.w};
    unsigned uu[4] = {u.x, u.y, u.z, u.w};
    #pragma unroll
    for (int h = 0; h < 4; ++h) {
      a0[h * 2]     = fmaxf(a0[h * 2],     bf2f((ushort_t)(vv[h] & 0xffff)) * wg);
      a0[h * 2 + 1] = fmaxf(a0[h * 2 + 1], bf2f((ushort_t)(vv[h] >> 16)) * wg);
      a1[h * 2]     = fmaxf(a1[h * 2],     bf2f((ushort_t)(uu[h] & 0xffff)) * wg);
      a1[h * 2 + 1] = fmaxf(a1[h * 2 + 1], bf2f((ushort_t)(uu[h] >> 16)) * wg);
    }
  }
  #pragma unroll
  for (int j = 0; j < 8; ++j) {
    a0[j] = fmaxf(a0[j], __shfl_xor(a0[j], 16));
    a0[j] = fmaxf(a0[j], __shfl_xor(a0[j], 32));
    a1[j] = fmaxf(a1[j], __shfl_xor(a1[j], 16));
    a1[j] = fmaxf(a1[j], __shfl_xor(a1[j], 32));
  }
  if (lane < 16) {
    #pragma unroll
    for (int j = 0; j < 8; ++j) {
      feat[wv][c8 * 8 + j] = lrelu(a0[j]);        // sfp -> [0,128)
      feat[wv][160 + c8 * 8 + j] = lrelu(a1[j]);  // sf  -> [160,288)
    }
  }
  if (lane < 32) feat[wv][128 + lane] = lrelu(vimf);
  feat[wv][288 + lane * 2] = lrelu(bf2f((ushort_t)(vcf & 0xffff)));
  feat[wv][288 + lane * 2 + 1] = lrelu(bf2f((ushort_t)(vcf >> 16)));
  // same-wave LDS producer/consumer: no barrier needed

  // ---- final GEMV (coalesced fwp2) ----
  int ch = lane & 31, half = lane >> 5;
  float acc = half ? 0.f : fb[ch];
  const float* wr = fwp2 + (half * 52) * 128 + ch * 4;
  const float* fr = &feat[wv][half * 208];
  #pragma unroll 4
  for (int j4 = 0; j4 < 52; ++j4) {
    float4 w4 = *(const float4*)(wr + j4 * 128);
    float4 f4 = *(const float4*)(fr + j4 * 4);
    acc = fmaf(f4.x, w4.x, fmaf(f4.y, w4.y, fmaf(f4.z, w4.z, fmaf(f4.w, w4.w, acc))));
  }
  acc += __shfl_xor(acc, 32);
  if (lane < 32) out[(size_t)ch * N + pid] = acc;
}

// ---------------------------------------------------------------------------
extern "C" void kernel_launch(void* const* d_in, const int* in_sizes, int n_in,
                              void* d_out, int out_size, void* d_ws, size_t ws_size,
                              hipStream_t stream) {
  const float* img   = (const float*)d_in[0];
  const float* cloud = (const float*)d_in[1];
  const float* c1w   = (const float*)d_in[2];
  const float* c1b   = (const float*)d_in[3];
  const float* c2w   = (const float*)d_in[4];
  const float* c2b   = (const float*)d_in[5];
  const float* ps1w  = (const float*)d_in[6];
  const float* ps1b  = (const float*)d_in[7];
  const float* ps2w  = (const float*)d_in[8];
  const float* ps2b  = (const float*)d_in[9];
  const float* p1w   = (const float*)d_in[10];
  const float* p1b   = (const float*)d_in[11];
  const float* p2w   = (const float*)d_in[12];
  const float* p2b   = (const float*)d_in[13];
  const float* fw    = (const float*)d_in[14];
  const float* fb    = (const float*)d_in[15];
  float* out = (float*)d_out;

  char* ws = (char*)d_ws;
  float4*   pts4  = (float4*)(ws + 0);             // 256 KB
  ushort_t* cfh   = (ushort_t*)(ws + 262144);      // 4 MB
  ushort_t* imfh  = (ushort_t*)(ws + 4456448);     // 1 MB
  ushort_t* w1h   = (ushort_t*)(ws + 7602176);     // 64 KB
  ushort_t* w2h   = (ushort_t*)(ws + 7667712);     // 64 KB
  ushort_t* c1h   = (ushort_t*)(ws + 7733248);     // 4 KB
  ushort_t* c2h   = (ushort_t*)(ws + 7737344);     // 16 KB
  ushort_t* ycf   = (ushort_t*)(ws + 7753472);     // 4 MB
  ushort_t* yimg  = (ushort_t*)(ws + 11947776);    // 4 MB
  float4*   spts  = (float4*)(ws + 16142080);      // 256 KB
  int*      cellStart = (int*)(ws + 16404224);     // 32 KB (4097 used)
  int*      cellofs   = (int*)(ws + 16436992);     // 16 KB
  int*      count     = (int*)(ws + 16453376);     // 16 KB
  float*    fwp2      = (float*)(ws + 16469760);   // 53 KB

  hipMemsetAsync(count, 0, NCELL * sizeof(int), stream);
  prepw_kernel<<<604, 256, 0, stream>>>(img, cloud, p1w, p1b, p2w, p2b,
                                        ps1w, ps2w, c1w, c2w, fw,
                                        pts4, cfh, imfh, w1h, w2h, c1h, c2h,
                                        fwp2, count);
  scan_kernel<<<1, 256, 0, stream>>>(count, cellStart, cellofs);
  scatter_kernel<<<64, 256, 0, stream>>>(pts4, cellofs, spts);
  ymlp_kernel<<<512, 256, 0, stream>>>(cfh, imfh, w1h, ps1b, w2h, ps2b,
                                       c1h, c1b, c2h, c2b, ycf, yimg);
  knng_kernel<<<N / 4, 256, 0, stream>>>(pts4, spts, cellStart,
                                         ycf, yimg, cfh, imfh,
                                         fwp2, fb, out);
}